// Round 9
// baseline (284.041 us; speedup 1.0000x reference)
//
#include <hip/hip_runtime.h>
#include <math.h>

// Problem constants (fixed by reference setup_inputs)
#define NQ    2048      // B*QB
#define Dd    256
#define NHh   8
#define HDd   32
#define KK    164       // 9+25+49+81
#define KP    192       // padded K (6 full 32-tiles)
#define PPB   5440      // valid cells per batch: 64+256+1024+4096
#define M_TOT 21760     // 4 * PPB
#define TWO_D 512

using bf16x8  = __attribute__((ext_vector_type(8))) short;
using f32x4   = __attribute__((ext_vector_type(4))) float;
using ushort8 = __attribute__((ext_vector_type(8))) unsigned short;

__device__ __forceinline__ unsigned short bf16_rne(float x) {
    unsigned u = __float_as_uint(x);
    return (unsigned short)((u + 0x7fffu + ((u >> 16) & 1u)) >> 16);
}
__device__ __forceinline__ float bf2f(unsigned short h) {
    return __uint_as_float((unsigned)h << 16);
}

__device__ __forceinline__ void gload_lds16(const void* g, void* s) {
    __builtin_amdgcn_global_load_lds(
        (const __attribute__((address_space(1))) void*)g,
        (__attribute__((address_space(3))) void*)s, 16, 0, 0);
}

__device__ __forceinline__ void row_geom(int r, int& l, int& S, int& base, int& lg, int& inv) {
    if      (r < 64)   { l = 0; S = 8;  base = 0;    lg = 3; inv = 8; }
    else if (r < 320)  { l = 1; S = 16; base = 64;   lg = 4; inv = 4; }
    else if (r < 1344) { l = 2; S = 32; base = 320;  lg = 5; inv = 2; }
    else               { l = 3; S = 64; base = 1344; lg = 6; inv = 1; }
}

// ---------------------------------------------------------------------------
// prep (fused): blocks [0,5440) gather+split fmap; [5440,5952) split Wkv;
// [5952,6208) split Wq; [6208,6464) split Wout; [6464,8512) LN+split query.
// ---------------------------------------------------------------------------
__device__ __forceinline__ void split_one(const float* __restrict__ W,
                                          unsigned short* __restrict__ hi_,
                                          unsigned short* __restrict__ lo_,
                                          int N, int gid) {
    int k = gid & 255, n = gid >> 8;
    float x = W[k * N + n];
    unsigned short h = bf16_rne(x);
    hi_[n * 256 + k] = h;
    lo_[n * 256 + k] = bf16_rne(x - bf2f(h));
}

__global__ __launch_bounds__(256) void prep(const float* __restrict__ fmap,
                                            const float* __restrict__ Wkv,
                                            const float* __restrict__ Wq,
                                            const float* __restrict__ Wout,
                                            const float* __restrict__ query,
                                            const float* __restrict__ gamma,
                                            const float* __restrict__ beta,
                                            unsigned short* __restrict__ Ahi,
                                            unsigned short* __restrict__ Alo,
                                            unsigned short* __restrict__ WkvThi,
                                            unsigned short* __restrict__ WkvTlo,
                                            unsigned short* __restrict__ WqThi,
                                            unsigned short* __restrict__ WqTlo,
                                            unsigned short* __restrict__ WoThi,
                                            unsigned short* __restrict__ WoTlo,
                                            unsigned short* __restrict__ Xhi,
                                            unsigned short* __restrict__ Xlo) {
    __shared__ float red[4];
    const int bid = blockIdx.x, t = threadIdx.x;

    if (bid < 5440) {
        // gather valid cells, split fp32 -> bf16 hi/lo, compacted [m][256]
        int gid = bid * 256 + t;
        int m = gid >> 6, c4 = (gid & 63) << 2;
        int b = m / PPB, r = m - b * PPB;
        int l, S, base, lg, inv;
        row_geom(r, l, S, base, lg, inv);
        int idx = r - base;
        int i = idx >> lg, j = idx & (S - 1);
        size_t rowOff = ((size_t)((b * 64 + i) * 64 + j)) * 1024 + l * 256;
        const float4 v = *(const float4*)(fmap + rowOff + c4);
        ushort4 hi, lo;
        hi.x = bf16_rne(v.x); lo.x = bf16_rne(v.x - bf2f(hi.x));
        hi.y = bf16_rne(v.y); lo.y = bf16_rne(v.y - bf2f(hi.y));
        hi.z = bf16_rne(v.z); lo.z = bf16_rne(v.z - bf2f(hi.z));
        hi.w = bf16_rne(v.w); lo.w = bf16_rne(v.w - bf2f(hi.w));
        *(ushort4*)(Ahi + (size_t)m * 256 + c4) = hi;
        *(ushort4*)(Alo + (size_t)m * 256 + c4) = lo;
    } else if (bid < 5952) {
        split_one(Wkv, WkvThi, WkvTlo, 512, (bid - 5440) * 256 + t);
    } else if (bid < 6208) {
        split_one(Wq, WqThi, WqTlo, 256, (bid - 5952) * 256 + t);
    } else if (bid < 6464) {
        split_one(Wout, WoThi, WoTlo, 256, (bid - 6208) * 256 + t);
    } else {
        // LayerNorm + split
        const int q = bid - 6464, wid = t >> 6;
        float x = query[q * Dd + t];
        float s = x;
#pragma unroll
        for (int mK = 32; mK >= 1; mK >>= 1) s += __shfl_xor(s, mK);
        if ((t & 63) == 0) red[wid] = s;
        __syncthreads();
        float mu = (red[0] + red[1] + red[2] + red[3]) * (1.0f / 256.0f);
        float dx = x - mu;
        float s2 = dx * dx;
#pragma unroll
        for (int mK = 32; mK >= 1; mK >>= 1) s2 += __shfl_xor(s2, mK);
        __syncthreads();
        if ((t & 63) == 0) red[wid] = s2;
        __syncthreads();
        float var = (red[0] + red[1] + red[2] + red[3]) * (1.0f / 256.0f);
        float v = dx * rsqrtf(var + 1e-5f) * gamma[t] + beta[t];
        unsigned short hi = bf16_rne(v);
        Xhi[q * Dd + t] = hi;
        Xlo[q * Dd + t] = bf16_rne(v - bf2f(hi));
    }
}

// ---------------------------------------------------------------------------
// KV = A @ Wkv via split-bf16 MFMA (M=21760, N=512, Kexp=768, 3 segments).
// Grid (4, 170): N-tiles adjacent in dispatch -> A-panel L2 reuse.
// bf16 output; RoPE applied to the K half (n<256) in the epilogue (the
// shfl_xor packing pair IS the RoPE rotation pair).
// ---------------------------------------------------------------------------
__global__ __launch_bounds__(256) void kv_gemm_mfma(const unsigned short* __restrict__ Ahi,
                                                    const unsigned short* __restrict__ Alo,
                                                    const unsigned short* __restrict__ Bthi,
                                                    const unsigned short* __restrict__ Btlo,
                                                    const float* __restrict__ freqs,
                                                    unsigned short* __restrict__ kv16) {
    __shared__ __align__(16) short As[2][128 * 32];
    __shared__ __align__(16) short Bs[2][128 * 32];

    const int t  = threadIdx.x;
    const int w  = t >> 6, l = t & 63;
    const int wr = w >> 1, wc = w & 1;
    const int n0 = blockIdx.x * 128, bm = blockIdx.y * 128;
    const int lr = l & 15, ks = l >> 4;
    const int ksw8 = ((ks ^ ((lr >> 1) & 3)) << 3);
    const bool doRope = (n0 < 256);

    f32x4 acc[4][4];
#pragma unroll
    for (int i = 0; i < 4; i++)
#pragma unroll
        for (int j = 0; j < 4; j++) { f32x4 z = {0.f,0.f,0.f,0.f}; acc[i][j] = z; }

    const int srow = l >> 2, sslot = l & 3;
    const int gs = sslot ^ ((srow >> 1) & 3);

    auto stage = [&](int kt, int buf) {
        int seg = kt >> 3;
        const unsigned short* Aseg = (seg < 2) ? Ahi : Alo;
        const unsigned short* Bseg = (seg == 1) ? Btlo : Bthi;
        size_t k0b = (size_t)((kt & 7) << 6);
#pragma unroll
        for (int i = 0; i < 2; i++) {
            int rb = w * 32 + i * 16;
            int m  = rb + srow;
            gload_lds16((const char*)Aseg + (((size_t)(bm + m)) << 9) + k0b + (gs << 4),
                        (void*)&As[buf][rb * 32]);
            gload_lds16((const char*)Bseg + (((size_t)(n0 + m)) << 9) + k0b + (gs << 4),
                        (void*)&Bs[buf][rb * 32]);
        }
    };

    stage(0, 0);
    __syncthreads();

    for (int kt = 0; kt < 24; kt++) {
        int cur = kt & 1;
        if (kt < 23) stage(kt + 1, cur ^ 1);

        bf16x8 afr[4], bfr[4];
#pragma unroll
        for (int f = 0; f < 4; f++) {
            int m = wr * 64 + f * 16 + lr;
            afr[f] = *(const bf16x8*)&As[cur][m * 32 + ksw8];
            int n = wc * 64 + f * 16 + lr;
            bfr[f] = *(const bf16x8*)&Bs[cur][n * 32 + ksw8];
        }
#pragma unroll
        for (int i = 0; i < 4; i++)
#pragma unroll
            for (int j = 0; j < 4; j++)
                acc[i][j] = __builtin_amdgcn_mfma_f32_16x16x32_bf16(afr[i], bfr[j],
                                                                    acc[i][j], 0, 0, 0);
        __syncthreads();
    }

    // epilogue: C/D layout col = lane&15, row = (lane>>4)*4 + reg.
    // lanes lr/lr^1 hold adjacent columns: RoPE-rotate (K half), pack, store.
#pragma unroll
    for (int i = 0; i < 4; i++) {
        int mg = bm + wr * 64 + i * 16 + ks * 4;
#pragma unroll
        for (int r = 0; r < 4; r++) {
            int m = mg + r;
            float px = 0.f, py = 0.f, pl = 0.f;
            if (doRope) {
                int b = m / PPB;
                int rr = m - b * PPB;
                int lL, S, base, lg, inv;
                row_geom(rr, lL, S, base, lg, inv);
                int idx = rr - base;
                px = (float)((idx >> lg) * inv);
                py = (float)((idx & (S - 1)) * inv);
                pl = (float)lL;
            }
#pragma unroll
            for (int j = 0; j < 4; j++) {
                int ng = n0 + wc * 64 + j * 16 + lr;
                float self = acc[i][j][r];
                float part = __shfl_xor(self, 1);
                if (!(lr & 1)) {
                    float y1 = self, y2 = part;
                    if (doRope) {
                        int f = (ng & 31) >> 1;
                        float ang = px * freqs[f] + py * freqs[16 + f] + pl * freqs[32 + f];
                        float c = cosf(ang), s = sinf(ang);
                        y1 = self * c - part * s;
                        y2 = self * s + part * c;
                    }
                    unsigned word = (unsigned)bf16_rne(y1) | ((unsigned)bf16_rne(y2) << 16);
                    *(unsigned*)(kv16 + (size_t)m * TWO_D + ng) = word;
                }
            }
        }
    }
}

// ---------------------------------------------------------------------------
// proj GEMM: C(2048x256) = A(2048x256) @ W(256x256) [+resid], split-bf16 MFMA
// BM=64, BN=32 -> grid (8,32) = 256 blocks (all CUs). 4 waves stacked on M.
// ---------------------------------------------------------------------------
template<bool RESID>
__global__ __launch_bounds__(256) void proj_gemm(const unsigned short* __restrict__ Ahi,
                                                 const unsigned short* __restrict__ Alo,
                                                 const unsigned short* __restrict__ Bthi,
                                                 const unsigned short* __restrict__ Btlo,
                                                 float* __restrict__ C,
                                                 const float* __restrict__ resid) {
    __shared__ __align__(16) short As[2][64 * 32];
    __shared__ __align__(16) short Bs[2][32 * 32];

    const int t  = threadIdx.x;
    const int w  = t >> 6, l = t & 63;
    const int n0 = blockIdx.x * 32, bm = blockIdx.y * 64;
    const int lr = l & 15, ks = l >> 4;
    const int ksw8 = ((ks ^ ((lr >> 1) & 3)) << 3);

    f32x4 acc[2];
#pragma unroll
    for (int j = 0; j < 2; j++) { f32x4 z = {0.f,0.f,0.f,0.f}; acc[j] = z; }

    const int srow = l >> 2, sslot = l & 3;
    const int gs = sslot ^ ((srow >> 1) & 3);

    auto stage = [&](int kt, int buf) {
        int seg = kt >> 3;
        const unsigned short* Aseg = (seg < 2) ? Ahi : Alo;
        const unsigned short* Bseg = (seg == 1) ? Btlo : Bthi;
        size_t k0b = (size_t)((kt & 7) << 6);
        {
            int rb = w * 16;
            int m  = rb + srow;
            gload_lds16((const char*)Aseg + (((size_t)(bm + m)) << 9) + k0b + (gs << 4),
                        (void*)&As[buf][rb * 32]);
        }
        if (w < 2) {
            int rb = w * 16;
            int m  = rb + srow;
            gload_lds16((const char*)Bseg + (((size_t)(n0 + m)) << 9) + k0b + (gs << 4),
                        (void*)&Bs[buf][rb * 32]);
        }
    };

    stage(0, 0);
    __syncthreads();

    for (int kt = 0; kt < 24; kt++) {
        int cur = kt & 1;
        if (kt < 23) stage(kt + 1, cur ^ 1);

        bf16x8 afr, bfr[2];
        {
            int m = w * 16 + lr;
            afr = *(const bf16x8*)&As[cur][m * 32 + ksw8];
        }
#pragma unroll
        for (int j = 0; j < 2; j++) {
            int n = j * 16 + lr;
            bfr[j] = *(const bf16x8*)&Bs[cur][n * 32 + ksw8];
        }
#pragma unroll
        for (int j = 0; j < 2; j++)
            acc[j] = __builtin_amdgcn_mfma_f32_16x16x32_bf16(afr, bfr[j], acc[j], 0, 0, 0);
        __syncthreads();
    }

    {
        int mg = bm + w * 16 + ks * 4;
#pragma unroll
        for (int j = 0; j < 2; j++) {
            int ng = n0 + j * 16 + lr;
#pragma unroll
            for (int r = 0; r < 4; r++) {
                float v = acc[j][r];
                if (RESID) v += resid[(size_t)(mg + r) * 256 + ng];
                C[(size_t)(mg + r) * 256 + ng] = v;
            }
        }
    }
}

// ---------------------------------------------------------------------------
// attention core: RoPE(q) + scores -> softmax -> PV, bf16 KV.
// XCD-cluster swizzle: q = (bid&7)*256 + bid>>3.
// ---------------------------------------------------------------------------
__global__ __launch_bounds__(256) void attn_core(const float* __restrict__ qr,
                                                 const float* __restrict__ qpos,
                                                 const unsigned short* __restrict__ kv16,
                                                 const float* __restrict__ freqs,
                                                 unsigned short* __restrict__ Phi,
                                                 unsigned short* __restrict__ Plo) {
    __shared__ __align__(16) float qsh[Dd];
    __shared__ float sL[NHh * KP];
    __shared__ int   kidx[KP];
    __shared__ float attnP[8][Dd];
    __shared__ float invS[NHh];

    const int q = ((blockIdx.x & 7) << 8) | (blockIdx.x >> 3);
    const int t = threadIdx.x;
    const int h = t >> 5, lane = t & 31;

    float qx = qpos[q * 4 + 1];
    float qy = qpos[q * 4 + 2];
    int   bb = (int)qpos[q * 4 + 0];

    // ---- load q row + RoPE in-register (pairs are adjacent lanes) ----
    {
        float x = qr[q * Dd + t];
        int f = (t & 31) >> 1;
        float ang = qx * freqs[f] + qy * freqs[16 + f] + 3.0f * freqs[32 + f];
        float c = cosf(ang), sn = sinf(ang);
        float partner = __shfl_xor(x, 1);
        qsh[t] = (!(t & 1)) ? (x * c - partner * sn) : (partner * sn + x * c);
    }

    if (t < KP) {
        int k = t;
        int kv = -1;
        if (k < KK) {
            int S, base, off, sz, half, lg;
            if      (k < 9)  { S = 8;  base = 0;    off = k;      sz = 3; half = 1; lg = 3; }
            else if (k < 34) { S = 16; base = 64;   off = k - 9;  sz = 5; half = 2; lg = 4; }
            else if (k < 83) { S = 32; base = 320;  off = k - 34; sz = 7; half = 3; lg = 5; }
            else             { S = 64; base = 1344; off = k - 83; sz = 9; half = 4; lg = 6; }
            int di = off / sz - half;
            int dj = off % sz - half;
            float scal = (float)S * (1.0f / 64.0f);
            int ci = (int)floorf(qx * scal);
            int cj = (int)floorf(qy * scal);
            int i = ci + di, j = cj + dj;
            bool valid = (i >= 0) & (i < S) & (j >= 0) & (j < S);
            kv = valid ? (bb * PPB + base + (i << lg) + j) : -1;
        }
        kidx[t] = kv;
    }
    __syncthreads();

    // ---- scores: thread (h, lane) owns 6 k's; K rows are bf16 ----
    float qreg[32];
#pragma unroll
    for (int i = 0; i < 32; i++) qreg[i] = qsh[h * HDd + i];

#pragma unroll
    for (int ct = 0; ct < 6; ++ct) {
        int k = ct * 32 + lane;
        int ki = kidx[k];
        int kr = ki < 0 ? 0 : ki;
        const ushort8* kp = (const ushort8*)(kv16 + (size_t)kr * TWO_D + h * HDd);
        float c0 = 0.f, c1 = 0.f;
#pragma unroll
        for (int s4 = 0; s4 < 4; s4++) {
            ushort8 kvv = kp[s4];
            float* cc = (s4 & 1) ? &c1 : &c0;
#pragma unroll
            for (int e = 0; e < 8; e++)
                *cc = fmaf(qreg[s4 * 8 + e], bf2f(kvv[e]), *cc);
        }
        sL[h * KP + k] = (ki >= 0) ? (c0 + c1) : -INFINITY;
    }
    __syncthreads();

    // ---- softmax per head ----
    float mx = -INFINITY;
#pragma unroll
    for (int ct = 0; ct < 6; ++ct) mx = fmaxf(mx, sL[h * KP + ct * 32 + lane]);
#pragma unroll
    for (int mK = 16; mK >= 1; mK >>= 1) mx = fmaxf(mx, __shfl_xor(mx, mK));
    float se = 0.f;
#pragma unroll
    for (int ct = 0; ct < 6; ++ct) {
        int k = ct * 32 + lane;
        float e = __expf(sL[h * KP + k] - mx);
        sL[h * KP + k] = e;
        se += e;
    }
#pragma unroll
    for (int mK = 16; mK >= 1; mK >>= 1) se += __shfl_xor(se, mK);
    if (lane == 0) invS[h] = 1.0f / se;
    __syncthreads();

    // ---- PV: half-wave reads full 512B bf16 V row; 2 rows in flight/wave ----
    {
        const int rep  = t >> 6;
        const int half = (t >> 5) & 1;
        const int l5   = t & 31;
        const int hh   = l5 >> 2;
        const int oct  = l5 & 3;
        float a[8];
#pragma unroll
        for (int e = 0; e < 8; e++) a[e] = 0.f;
        const unsigned short* vbase = kv16 + Dd + hh * HDd + oct * 8;
#pragma unroll 4
        for (int it = 0; it < 24; it++) {
            int k = rep * 48 + it * 2 + half;
            float w0 = sL[hh * KP + k];
            int kr = kidx[k]; kr = kr < 0 ? 0 : kr;
            ushort8 vv = *(const ushort8*)(vbase + (size_t)kr * TWO_D);
#pragma unroll
            for (int e = 0; e < 8; e++) a[e] = fmaf(w0, bf2f(vv[e]), a[e]);
        }
        float* dst = &attnP[t >> 5][hh * HDd + oct * 8];
#pragma unroll
        for (int e = 0; e < 8; e++) dst[e] = a[e];
    }
    __syncthreads();

    float val = 0.f;
#pragma unroll
    for (int s = 0; s < 8; s++) val += attnP[s][t];
    val *= invS[h];
    unsigned short hi = bf16_rne(val);
    Phi[q * Dd + t] = hi;
    Plo[q * Dd + t] = bf16_rne(val - bf2f(hi));
}

// ---------------------------------------------------------------------------
// Fallback: fp32 pipeline if ws too small
// ---------------------------------------------------------------------------
#define BMf 128
#define BNf 128
#define KTf 16

__global__ __launch_bounds__(256) void kv_gemm(const float* __restrict__ fmap,
                                               const float* __restrict__ Wkv,
                                               float* __restrict__ kvws) {
    __shared__ float Asf[KTf][BMf + 4];
    __shared__ float Bsf[KTf][BNf + 4];
    __shared__ int   rowOff[BMf];

    const int t  = threadIdx.x;
    const int bm = blockIdx.x * BMf;
    const int n0 = blockIdx.y * BNf;

    if (t < BMf) {
        int m = bm + t;
        int b = m / PPB;
        int r = m - b * PPB;
        int l, S, base, lg, inv;
        row_geom(r, l, S, base, lg, inv);
        int idx = r - base;
        int i = idx >> lg;
        int j = idx & (S - 1);
        rowOff[t] = ((b * 64 + i) * 64 + j) * 1024 + l * 256;
    }
    __syncthreads();

    const int tx = t & 15, ty = t >> 4;
    float acc[8][8];
#pragma unroll
    for (int i = 0; i < 8; i++)
#pragma unroll
        for (int j = 0; j < 8; j++) acc[i][j] = 0.f;

    for (int k0 = 0; k0 < Dd; k0 += KTf) {
#pragma unroll
        for (int s = 0; s < 2; s++) {
            int task = t + s * 256;
            int row  = task >> 2;
            int k4   = (task & 3) * 4;
            const float4 v = *(const float4*)(fmap + rowOff[row] + k0 + k4);
            Asf[k4 + 0][row] = v.x;
            Asf[k4 + 1][row] = v.y;
            Asf[k4 + 2][row] = v.z;
            Asf[k4 + 3][row] = v.w;
        }
#pragma unroll
        for (int s = 0; s < 2; s++) {
            int task = t + s * 256;
            int kk   = task >> 5;
            int c4   = (task & 31) * 4;
            *(float4*)(&Bsf[kk][c4]) = *(const float4*)(Wkv + (k0 + kk) * TWO_D + n0 + c4);
        }
        __syncthreads();
#pragma unroll
        for (int kk = 0; kk < KTf; kk++) {
            float a[8], bb[8];
#pragma unroll
            for (int i = 0; i < 8; i++) a[i]  = Asf[kk][ty * 8 + i];
#pragma unroll
            for (int j = 0; j < 8; j++) bb[j] = Bsf[kk][tx * 8 + j];
#pragma unroll
            for (int i = 0; i < 8; i++)
#pragma unroll
                for (int j = 0; j < 8; j++)
                    acc[i][j] = fmaf(a[i], bb[j], acc[i][j]);
        }
        __syncthreads();
    }

#pragma unroll
    for (int i = 0; i < 8; i++) {
        int m = bm + ty * 8 + i;
        float* dst = kvws + (size_t)m * TWO_D + n0 + tx * 8;
#pragma unroll
        for (int j = 0; j < 8; j += 4) {
            *(float4*)(dst + j) = make_float4(acc[i][j], acc[i][j + 1],
                                              acc[i][j + 2], acc[i][j + 3]);
        }
    }
}

__global__ __launch_bounds__(256) void rope_k_f32(float* __restrict__ kvws,
                                                  const float* __restrict__ freqs) {
    int gid = blockIdx.x * 256 + threadIdx.x;
    int m = gid >> 7;
    int p = gid & 127;
    int f = p & 15;
    int b = m / PPB;
    int r = m - b * PPB;
    int l, S, base, lg, inv;
    row_geom(r, l, S, base, lg, inv);
    int idx = r - base;
    int i = idx >> lg;
    int j = idx & (S - 1);
    float px = (float)(i * inv), py = (float)(j * inv), pl = (float)l;
    float ang = px * freqs[f] + py * freqs[16 + f] + pl * freqs[32 + f];
    float c = cosf(ang), s = sinf(ang);
    float2* kp = (float2*)kvws + (size_t)m * 256 + p;
    float2 v = *kp;
    *kp = make_float2(v.x * c - v.y * s, v.x * s + v.y * c);
}

__global__ __launch_bounds__(256) void attn_fused(const float* __restrict__ query,
                                                  const float* __restrict__ qpos,
                                                  const float* __restrict__ Wq,
                                                  const float* __restrict__ Wout,
                                                  const float* __restrict__ gamma,
                                                  const float* __restrict__ beta,
                                                  const float* __restrict__ freqs,
                                                  const float* __restrict__ kvws,
                                                  float* __restrict__ out) {
    __shared__ float qn[Dd];
    __shared__ __align__(16) float qsh[Dd];
    __shared__ float sL[NHh * KK];
    __shared__ int   kidx[KK];
    __shared__ float attnL[Dd];
    __shared__ float red[4];
    __shared__ float invS[NHh];

    const int q = blockIdx.x;
    const int t = threadIdx.x;
    const int wid = t >> 6;
    const int h = t >> 5, lane = t & 31;

    float x = query[q * Dd + t];
    float s = x;
#pragma unroll
    for (int mK = 32; mK >= 1; mK >>= 1) s += __shfl_xor(s, mK);
    if ((t & 63) == 0) red[wid] = s;
    __syncthreads();
    float mu = (red[0] + red[1] + red[2] + red[3]) * (1.0f / 256.0f);
    float dx = x - mu;
    float s2 = dx * dx;
#pragma unroll
    for (int mK = 32; mK >= 1; mK >>= 1) s2 += __shfl_xor(s2, mK);
    __syncthreads();
    if ((t & 63) == 0) red[wid] = s2;
    __syncthreads();
    float var = (red[0] + red[1] + red[2] + red[3]) * (1.0f / 256.0f);
    float rs = rsqrtf(var + 1e-5f);
    qn[t] = dx * rs * gamma[t] + beta[t];
    __syncthreads();

    float a0 = 0.f, a1 = 0.f, a2 = 0.f, a3 = 0.f;
#pragma unroll 8
    for (int d = 0; d < Dd; d += 4) {
        a0 = fmaf(qn[d + 0], Wq[(d + 0) * Dd + t], a0);
        a1 = fmaf(qn[d + 1], Wq[(d + 1) * Dd + t], a1);
        a2 = fmaf(qn[d + 2], Wq[(d + 2) * Dd + t], a2);
        a3 = fmaf(qn[d + 3], Wq[(d + 3) * Dd + t], a3);
    }
    float acc = (a0 + a1) + (a2 + a3);

    float qx = qpos[q * 4 + 1];
    float qy = qpos[q * 4 + 2];
    int   bb = (int)qpos[q * 4 + 0];
    {
        int f = (t & 31) >> 1;
        float ang = qx * freqs[f] + qy * freqs[16 + f] + 3.0f * freqs[32 + f];
        float c = cosf(ang), sn = sinf(ang);
        float partner = __shfl_xor(acc, 1);
        bool ev = !(t & 1);
        acc = ev ? (acc * c - partner * sn) : (partner * sn + acc * c);
    }
    qsh[t] = acc;

    if (t < KK) {
        int k = t;
        int S, base, off, sz, half, lg;
        if      (k < 9)  { S = 8;  base = 0;    off = k;      sz = 3; half = 1; lg = 3; }
        else if (k < 34) { S = 16; base = 64;   off = k - 9;  sz = 5; half = 2; lg = 4; }
        else if (k < 83) { S = 32; base = 320;  off = k - 34; sz = 7; half = 3; lg = 5; }
        else             { S = 64; base = 1344; off = k - 83; sz = 9; half = 4; lg = 6; }
        int di = off / sz - half;
        int dj = off % sz - half;
        float scal = (float)S * (1.0f / 64.0f);
        int ci = (int)floorf(qx * scal);
        int cj = (int)floorf(qy * scal);
        int i = ci + di, j = cj + dj;
        bool valid = (i >= 0) & (i < S) & (j >= 0) & (j < S);
        kidx[t] = valid ? (bb * PPB + base + (i << lg) + j) : -1;
    }
    __syncthreads();

    float4 qv[8];
    {
        const float4* qp = (const float4*)(qsh + h * HDd);
#pragma unroll
        for (int i = 0; i < 8; i++) qv[i] = qp[i];
    }
#pragma unroll
    for (int ct = 0; ct < 6; ++ct) {
        int k = ct * 32 + lane;
        if (k >= KK) break;
        int ki = kidx[k];
        int kr = ki < 0 ? 0 : ki;
        const float4* kp = (const float4*)(kvws + (size_t)kr * TWO_D + h * HDd);
        float c0 = 0.f, c1 = 0.f;
#pragma unroll
        for (int i = 0; i < 8; i += 2) {
            float4 k0v = kp[i], k1v = kp[i + 1];
            c0 = fmaf(qv[i].x, k0v.x, c0); c0 = fmaf(qv[i].y, k0v.y, c0);
            c0 = fmaf(qv[i].z, k0v.z, c0); c0 = fmaf(qv[i].w, k0v.w, c0);
            c1 = fmaf(qv[i + 1].x, k1v.x, c1); c1 = fmaf(qv[i + 1].y, k1v.y, c1);
            c1 = fmaf(qv[i + 1].z, k1v.z, c1); c1 = fmaf(qv[i + 1].w, k1v.w, c1);
        }
        sL[h * KK + k] = (ki >= 0) ? (c0 + c1) : -INFINITY;
    }
    __syncthreads();

    float mx = -INFINITY;
    for (int k = lane; k < KK; k += 32) mx = fmaxf(mx, sL[h * KK + k]);
#pragma unroll
    for (int mK = 16; mK >= 1; mK >>= 1) mx = fmaxf(mx, __shfl_xor(mx, mK));
    float se = 0.f;
    for (int k = lane; k < KK; k += 32) {
        float e = expf(sL[h * KK + k] - mx);
        sL[h * KK + k] = e;
        se += e;
    }
#pragma unroll
    for (int mK = 16; mK >= 1; mK >>= 1) se += __shfl_xor(se, mK);
    if (lane == 0) invS[h] = 1.0f / se;
    __syncthreads();

    float p0 = 0.f, p1 = 0.f, p2 = 0.f, p3 = 0.f;
#pragma unroll 4
    for (int k = 0; k < 164; k += 4) {
        int ki0 = kidx[k],     kr0 = ki0 < 0 ? 0 : ki0;
        int ki1 = kidx[k + 1], kr1 = ki1 < 0 ? 0 : ki1;
        int ki2 = kidx[k + 2], kr2 = ki2 < 0 ? 0 : ki2;
        int ki3 = kidx[k + 3], kr3 = ki3 < 0 ? 0 : ki3;
        p0 = fmaf(sL[h * KK + k],     kvws[(size_t)kr0 * TWO_D + Dd + t], p0);
        p1 = fmaf(sL[h * KK + k + 1], kvws[(size_t)kr1 * TWO_D + Dd + t], p1);
        p2 = fmaf(sL[h * KK + k + 2], kvws[(size_t)kr2 * TWO_D + Dd + t], p2);
        p3 = fmaf(sL[h * KK + k + 3], kvws[(size_t)kr3 * TWO_D + Dd + t], p3);
    }
    attnL[t] = ((p0 + p1) + (p2 + p3)) * invS[h];
    __syncthreads();

    float o0 = query[q * Dd + t], o1 = 0.f, o2 = 0.f, o3 = 0.f;
#pragma unroll 8
    for (int d = 0; d < Dd; d += 4) {
        o0 = fmaf(attnL[d + 0], Wout[(d + 0) * Dd + t], o0);
        o1 = fmaf(attnL[d + 1], Wout[(d + 1) * Dd + t], o1);
        o2 = fmaf(attnL[d + 2], Wout[(d + 2) * Dd + t], o2);
        o3 = fmaf(attnL[d + 3], Wout[(d + 3) * Dd + t], o3);
    }
    out[q * Dd + t] = (o0 + o1) + (o2 + o3);
}

// ---------------------------------------------------------------------------
extern "C" void kernel_launch(void* const* d_in, const int* in_sizes, int n_in,
                              void* d_out, int out_size, void* d_ws, size_t ws_size,
                              hipStream_t stream) {
    const float* query = (const float*)d_in[0];
    const float* qpos  = (const float*)d_in[1];
    const float* fmap  = (const float*)d_in[3];
    const float* gamma = (const float*)d_in[5];
    const float* beta  = (const float*)d_in[6];
    const float* Wq    = (const float*)d_in[7];
    const float* Wkv   = (const float*)d_in[8];
    const float* Wout  = (const float*)d_in[9];
    const float* freqs = (const float*)d_in[10];
    float* out = (float*)d_out;

    // flat (non-overlaid) workspace layout, all 4K-aligned
    const size_t O_KV16   = 0;            // 22,282,240
    const size_t O_AHI    = 22282240;     // 11,141,120
    const size_t O_ALO    = 33423360;     // 11,141,120
    const size_t O_WKVHI  = 44564480;     //    262,144
    const size_t O_WKVLO  = 44826624;     //    262,144
    const size_t O_WQHI   = 45088768;     //    131,072
    const size_t O_WQLO   = 45219840;     //    131,072
    const size_t O_WOHI   = 45350912;     //    131,072
    const size_t O_WOLO   = 45481984;     //    131,072
    const size_t O_XHI    = 45613056;     //  1,048,576
    const size_t O_XLO    = 46661632;     //  1,048,576
    const size_t O_QR     = 47710208;     //  2,097,152
    const size_t O_PHI    = 49807360;     //  1,048,576
    const size_t O_PLO    = 50855936;     //  1,048,576
    const size_t need     = 51904512;

    if (ws_size >= need) {
        char* base = (char*)d_ws;
        unsigned short* kv16   = (unsigned short*)(base + O_KV16);
        unsigned short* Ahi    = (unsigned short*)(base + O_AHI);
        unsigned short* Alo    = (unsigned short*)(base + O_ALO);
        unsigned short* WkvThi = (unsigned short*)(base + O_WKVHI);
        unsigned short* WkvTlo = (unsigned short*)(base + O_WKVLO);
        unsigned short* WqThi  = (unsigned short*)(base + O_WQHI);
        unsigned short* WqTlo  = (unsigned short*)(base + O_WQLO);
        unsigned short* WoThi  = (unsigned short*)(base + O_WOHI);
        unsigned short* WoTlo  = (unsigned short*)(base + O_WOLO);
        unsigned short* Xhi    = (unsigned short*)(base + O_XHI);
        unsigned short* Xlo    = (unsigned short*)(base + O_XLO);
        float*          qrw    = (float*)        (base + O_QR);
        unsigned short* Phi    = (unsigned short*)(base + O_PHI);
        unsigned short* Plo    = (unsigned short*)(base + O_PLO);

        prep<<<dim3(8512), 256, 0, stream>>>(fmap, Wkv, Wq, Wout, query, gamma, beta,
                                             Ahi, Alo, WkvThi, WkvTlo,
                                             WqThi, WqTlo, WoThi, WoTlo, Xhi, Xlo);
        kv_gemm_mfma<<<dim3(4, 170), 256, 0, stream>>>(Ahi, Alo, WkvThi, WkvTlo,
                                                       freqs, kv16);
        proj_gemm<false><<<dim3(8, 32), 256, 0, stream>>>(Xhi, Xlo, WqThi, WqTlo,
                                                          qrw, nullptr);
        attn_core<<<dim3(NQ), 256, 0, stream>>>(qrw, qpos, kv16, freqs, Phi, Plo);
        proj_gemm<true><<<dim3(8, 32), 256, 0, stream>>>(Phi, Plo, WoThi, WoTlo,
                                                         out, query);
    } else {
        float* kvws = (float*)d_ws;
        kv_gemm<<<dim3(M_TOT / BMf, TWO_D / BNf), 256, 0, stream>>>(fmap, Wkv, kvws);
        rope_k_f32<<<dim3((M_TOT * 128) / 256), 256, 0, stream>>>(kvws, freqs);
        attn_fused<<<dim3(NQ), 256, 0, stream>>>(query, qpos, Wq, Wout, gamma, beta,
                                                 freqs, kvws, out);
    }
}

// Round 11
// 197.849 us; speedup vs baseline: 1.4356x; 1.4356x over previous
//
#include <hip/hip_runtime.h>
#include <math.h>

// Problem constants (fixed by reference setup_inputs)
#define NQ    2048      // B*QB
#define Dd    256
#define NHh   8
#define HDd   32
#define KK    164       // 9+25+49+81
#define KP    192       // padded K (6 full 32-tiles)
#define PPB   5440      // valid cells per batch: 64+256+1024+4096
#define M_TOT 21760     // 4 * PPB
#define TWO_D 512

using bf16x8  = __attribute__((ext_vector_type(8))) short;
using f32x4   = __attribute__((ext_vector_type(4))) float;
using ushort8 = __attribute__((ext_vector_type(8))) unsigned short;

__device__ __forceinline__ unsigned short bf16_rne(float x) {
    unsigned u = __float_as_uint(x);
    return (unsigned short)((u + 0x7fffu + ((u >> 16) & 1u)) >> 16);
}
__device__ __forceinline__ float bf2f(unsigned short h) {
    return __uint_as_float((unsigned)h << 16);
}

__device__ __forceinline__ void gload_lds16(const void* g, void* s) {
    __builtin_amdgcn_global_load_lds(
        (const __attribute__((address_space(1))) void*)g,
        (__attribute__((address_space(3))) void*)s, 16, 0, 0);
}

__device__ __forceinline__ void row_geom(int r, int& l, int& S, int& base, int& lg, int& inv) {
    if      (r < 64)   { l = 0; S = 8;  base = 0;    lg = 3; inv = 8; }
    else if (r < 320)  { l = 1; S = 16; base = 64;   lg = 4; inv = 4; }
    else if (r < 1344) { l = 2; S = 32; base = 320;  lg = 5; inv = 2; }
    else               { l = 3; S = 64; base = 1344; lg = 6; inv = 1; }
}

// ---------------------------------------------------------------------------
// prep (fused): blocks [0,5440) gather+split fmap; [5440,5952) split Wkv;
// [5952,6208) split Wq; [6208,6464) split Wout; [6464,8512) LN+split query.
// ---------------------------------------------------------------------------
__device__ __forceinline__ void split_one(const float* __restrict__ W,
                                          unsigned short* __restrict__ hi_,
                                          unsigned short* __restrict__ lo_,
                                          int N, int gid) {
    int k = gid & 255, n = gid >> 8;
    float x = W[k * N + n];
    unsigned short h = bf16_rne(x);
    hi_[n * 256 + k] = h;
    lo_[n * 256 + k] = bf16_rne(x - bf2f(h));
}

__global__ __launch_bounds__(256) void prep(const float* __restrict__ fmap,
                                            const float* __restrict__ Wkv,
                                            const float* __restrict__ Wq,
                                            const float* __restrict__ Wout,
                                            const float* __restrict__ query,
                                            const float* __restrict__ gamma,
                                            const float* __restrict__ beta,
                                            unsigned short* __restrict__ Ahi,
                                            unsigned short* __restrict__ Alo,
                                            unsigned short* __restrict__ WkvThi,
                                            unsigned short* __restrict__ WkvTlo,
                                            unsigned short* __restrict__ WqThi,
                                            unsigned short* __restrict__ WqTlo,
                                            unsigned short* __restrict__ WoThi,
                                            unsigned short* __restrict__ WoTlo,
                                            unsigned short* __restrict__ Xhi,
                                            unsigned short* __restrict__ Xlo) {
    __shared__ float red[4];
    const int bid = blockIdx.x, t = threadIdx.x;

    if (bid < 5440) {
        int gid = bid * 256 + t;
        int m = gid >> 6, c4 = (gid & 63) << 2;
        int b = m / PPB, r = m - b * PPB;
        int l, S, base, lg, inv;
        row_geom(r, l, S, base, lg, inv);
        int idx = r - base;
        int i = idx >> lg, j = idx & (S - 1);
        size_t rowOff = ((size_t)((b * 64 + i) * 64 + j)) * 1024 + l * 256;
        const float4 v = *(const float4*)(fmap + rowOff + c4);
        ushort4 hi, lo;
        hi.x = bf16_rne(v.x); lo.x = bf16_rne(v.x - bf2f(hi.x));
        hi.y = bf16_rne(v.y); lo.y = bf16_rne(v.y - bf2f(hi.y));
        hi.z = bf16_rne(v.z); lo.z = bf16_rne(v.z - bf2f(hi.z));
        hi.w = bf16_rne(v.w); lo.w = bf16_rne(v.w - bf2f(hi.w));
        *(ushort4*)(Ahi + (size_t)m * 256 + c4) = hi;
        *(ushort4*)(Alo + (size_t)m * 256 + c4) = lo;
    } else if (bid < 5952) {
        split_one(Wkv, WkvThi, WkvTlo, 512, (bid - 5440) * 256 + t);
    } else if (bid < 6208) {
        split_one(Wq, WqThi, WqTlo, 256, (bid - 5952) * 256 + t);
    } else if (bid < 6464) {
        split_one(Wout, WoThi, WoTlo, 256, (bid - 6208) * 256 + t);
    } else {
        const int q = bid - 6464, wid = t >> 6;
        float x = query[q * Dd + t];
        float s = x;
#pragma unroll
        for (int mK = 32; mK >= 1; mK >>= 1) s += __shfl_xor(s, mK);
        if ((t & 63) == 0) red[wid] = s;
        __syncthreads();
        float mu = (red[0] + red[1] + red[2] + red[3]) * (1.0f / 256.0f);
        float dx = x - mu;
        float s2 = dx * dx;
#pragma unroll
        for (int mK = 32; mK >= 1; mK >>= 1) s2 += __shfl_xor(s2, mK);
        __syncthreads();
        if ((t & 63) == 0) red[wid] = s2;
        __syncthreads();
        float var = (red[0] + red[1] + red[2] + red[3]) * (1.0f / 256.0f);
        float v = dx * rsqrtf(var + 1e-5f) * gamma[t] + beta[t];
        unsigned short hi = bf16_rne(v);
        Xhi[q * Dd + t] = hi;
        Xlo[q * Dd + t] = bf16_rne(v - bf2f(hi));
    }
}

// ---------------------------------------------------------------------------
// KV = A @ Wkv via split-bf16 MFMA, co-staged 3-combo version.
// Per K-step (32 k): stage Ahi,Alo,Bhi,Blo together; run 48 MFMAs
// (AhiBhi + AhiBlo + AloBhi) per barrier -> 8 iterations instead of 24.
// XCD-grouped swizzle: the 4 N-tiles of an M-tile land on bids = same mod 8.
// RoPE fused in epilogue with fast __sincosf (2 angle pairs per (i,r)).
// ---------------------------------------------------------------------------
__global__ __launch_bounds__(256) void kv_gemm_mfma(const unsigned short* __restrict__ Ahi,
                                                    const unsigned short* __restrict__ Alo,
                                                    const unsigned short* __restrict__ Bthi,
                                                    const unsigned short* __restrict__ Btlo,
                                                    const float* __restrict__ freqs,
                                                    unsigned short* __restrict__ kv16) {
    __shared__ __align__(16) short As[2][2][128 * 32];   // [buf][hi/lo] 32 KB
    __shared__ __align__(16) short Bs[2][2][128 * 32];   // 32 KB

    // bids 0..703; xcd = bid%8. Group: y = (bid>>5)*8 + (bid&7), x = (bid>>3)&3.
    const int bid = blockIdx.x;
    const int my = (bid >> 5) * 8 + (bid & 7);
    const int mx = (bid >> 3) & 3;
    if (my >= 170) return;

    const int t  = threadIdx.x;
    const int w  = t >> 6, l = t & 63;
    const int wr = w >> 1, wc = w & 1;
    const int n0 = mx * 128, bm = my * 128;
    const int lr = l & 15, ks = l >> 4;
    const int ksw8 = ((ks ^ ((lr >> 1) & 3)) << 3);
    const bool doRope = (n0 < 256);

    f32x4 acc[4][4];
#pragma unroll
    for (int i = 0; i < 4; i++)
#pragma unroll
        for (int j = 0; j < 4; j++) { f32x4 z = {0.f,0.f,0.f,0.f}; acc[i][j] = z; }

    const int srow = l >> 2, sslot = l & 3;
    const int gs = sslot ^ ((srow >> 1) & 3);

    auto stage = [&](int kt, int buf) {
        size_t k0b = (size_t)(kt << 6);
#pragma unroll
        for (int i = 0; i < 2; i++) {
            int rb = w * 32 + i * 16;
            int m  = rb + srow;
            size_t aofs = (((size_t)(bm + m)) << 9) + k0b + (gs << 4);
            size_t bofs = (((size_t)(n0 + m)) << 9) + k0b + (gs << 4);
            gload_lds16((const char*)Ahi  + aofs, (void*)&As[buf][0][rb * 32]);
            gload_lds16((const char*)Alo  + aofs, (void*)&As[buf][1][rb * 32]);
            gload_lds16((const char*)Bthi + bofs, (void*)&Bs[buf][0][rb * 32]);
            gload_lds16((const char*)Btlo + bofs, (void*)&Bs[buf][1][rb * 32]);
        }
    };

    stage(0, 0);
    __syncthreads();

    for (int kt = 0; kt < 8; kt++) {
        int cur = kt & 1;
        if (kt < 7) stage(kt + 1, cur ^ 1);

        bf16x8 aH[4], aL[4], bH[4], bL[4];
#pragma unroll
        for (int f = 0; f < 4; f++) {
            int m = wr * 64 + f * 16 + lr;
            aH[f] = *(const bf16x8*)&As[cur][0][m * 32 + ksw8];
            aL[f] = *(const bf16x8*)&As[cur][1][m * 32 + ksw8];
            int n = wc * 64 + f * 16 + lr;
            bH[f] = *(const bf16x8*)&Bs[cur][0][n * 32 + ksw8];
            bL[f] = *(const bf16x8*)&Bs[cur][1][n * 32 + ksw8];
        }
#pragma unroll
        for (int i = 0; i < 4; i++)
#pragma unroll
            for (int j = 0; j < 4; j++)
                acc[i][j] = __builtin_amdgcn_mfma_f32_16x16x32_bf16(aH[i], bH[j],
                                                                    acc[i][j], 0, 0, 0);
#pragma unroll
        for (int i = 0; i < 4; i++)
#pragma unroll
            for (int j = 0; j < 4; j++)
                acc[i][j] = __builtin_amdgcn_mfma_f32_16x16x32_bf16(aH[i], bL[j],
                                                                    acc[i][j], 0, 0, 0);
#pragma unroll
        for (int i = 0; i < 4; i++)
#pragma unroll
            for (int j = 0; j < 4; j++)
                acc[i][j] = __builtin_amdgcn_mfma_f32_16x16x32_bf16(aL[i], bH[j],
                                                                    acc[i][j], 0, 0, 0);
        __syncthreads();
    }

    // epilogue: C/D layout col = lane&15, row = (lane>>4)*4 + reg.
    // f-index depends only on j&1: f = (j&1)*8 + (lr>>1) -> 2 angle pairs/(i,r).
    float fx0 = 0.f, fy0 = 0.f, fz0 = 0.f, fx1 = 0.f, fy1 = 0.f, fz1 = 0.f;
    if (doRope) {
        int e0 = lr >> 1, e1 = e0 + 8;
        fx0 = freqs[e0]; fy0 = freqs[16 + e0]; fz0 = freqs[32 + e0];
        fx1 = freqs[e1]; fy1 = freqs[16 + e1]; fz1 = freqs[32 + e1];
    }
#pragma unroll
    for (int i = 0; i < 4; i++) {
        int mg = bm + wr * 64 + i * 16 + ks * 4;
#pragma unroll
        for (int r = 0; r < 4; r++) {
            int m = mg + r;
            float c0 = 1.f, s0 = 0.f, c1 = 1.f, s1 = 0.f;
            if (doRope) {
                int b = m / PPB;
                int rw = m - b * PPB;
                int lL, S, base, lg, inv;
                row_geom(rw, lL, S, base, lg, inv);
                int idx = rw - base;
                float px = (float)((idx >> lg) * inv);
                float py = (float)((idx & (S - 1)) * inv);
                float pl = (float)lL;
                __sincosf(px * fx0 + py * fy0 + pl * fz0, &s0, &c0);
                __sincosf(px * fx1 + py * fy1 + pl * fz1, &s1, &c1);
            }
#pragma unroll
            for (int j = 0; j < 4; j++) {
                int ng = n0 + wc * 64 + j * 16 + lr;
                float self = acc[i][j][r];
                float part = __shfl_xor(self, 1);
                if (!(lr & 1)) {
                    float y1 = self, y2 = part;
                    if (doRope) {
                        float c = (j & 1) ? c1 : c0;
                        float s = (j & 1) ? s1 : s0;
                        y1 = self * c - part * s;
                        y2 = self * s + part * c;
                    }
                    unsigned word = (unsigned)bf16_rne(y1) | ((unsigned)bf16_rne(y2) << 16);
                    *(unsigned*)(kv16 + (size_t)m * TWO_D + ng) = word;
                }
            }
        }
    }
}

// ---------------------------------------------------------------------------
// proj GEMM, co-staged 3-combo: C(2048x256) = A @ W [+resid].
// BM=64, BN=32 -> grid (8,32) = 256 blocks. 8 K-iterations.
// ---------------------------------------------------------------------------
template<bool RESID>
__global__ __launch_bounds__(256) void proj_gemm(const unsigned short* __restrict__ Ahi,
                                                 const unsigned short* __restrict__ Alo,
                                                 const unsigned short* __restrict__ Bthi,
                                                 const unsigned short* __restrict__ Btlo,
                                                 float* __restrict__ C,
                                                 const float* __restrict__ resid) {
    __shared__ __align__(16) short As[2][2][64 * 32];   // 16 KB
    __shared__ __align__(16) short Bs[2][2][32 * 32];   // 8 KB

    const int t  = threadIdx.x;
    const int w  = t >> 6, l = t & 63;
    const int n0 = blockIdx.x * 32, bm = blockIdx.y * 64;
    const int lr = l & 15, ks = l >> 4;
    const int ksw8 = ((ks ^ ((lr >> 1) & 3)) << 3);

    f32x4 acc[2];
#pragma unroll
    for (int j = 0; j < 2; j++) { f32x4 z = {0.f,0.f,0.f,0.f}; acc[j] = z; }

    const int srow = l >> 2, sslot = l & 3;
    const int gs = sslot ^ ((srow >> 1) & 3);

    auto stage = [&](int kt, int buf) {
        size_t k0b = (size_t)(kt << 6);
        {
            int rb = w * 16;
            int m  = rb + srow;
            size_t aofs = (((size_t)(bm + m)) << 9) + k0b + (gs << 4);
            gload_lds16((const char*)Ahi + aofs, (void*)&As[buf][0][rb * 32]);
            gload_lds16((const char*)Alo + aofs, (void*)&As[buf][1][rb * 32]);
        }
        {
            int sel = w >> 1;            // waves 0,1 -> Bhi; 2,3 -> Blo
            int rb  = (w & 1) * 16;
            int m   = rb + srow;
            const unsigned short* Bp = sel ? Btlo : Bthi;
            size_t bofs = (((size_t)(n0 + m)) << 9) + k0b + (gs << 4);
            gload_lds16((const char*)Bp + bofs, (void*)&Bs[buf][sel][rb * 32]);
        }
    };

    stage(0, 0);
    __syncthreads();

    for (int kt = 0; kt < 8; kt++) {
        int cur = kt & 1;
        if (kt < 7) stage(kt + 1, cur ^ 1);

        bf16x8 aH, aL, bH[2], bL[2];
        {
            int m = w * 16 + lr;
            aH = *(const bf16x8*)&As[cur][0][m * 32 + ksw8];
            aL = *(const bf16x8*)&As[cur][1][m * 32 + ksw8];
        }
#pragma unroll
        for (int j = 0; j < 2; j++) {
            int n = j * 16 + lr;
            bH[j] = *(const bf16x8*)&Bs[cur][0][n * 32 + ksw8];
            bL[j] = *(const bf16x8*)&Bs[cur][1][n * 32 + ksw8];
        }
#pragma unroll
        for (int j = 0; j < 2; j++)
            acc[j] = __builtin_amdgcn_mfma_f32_16x16x32_bf16(aH, bH[j], acc[j], 0, 0, 0);
#pragma unroll
        for (int j = 0; j < 2; j++)
            acc[j] = __builtin_amdgcn_mfma_f32_16x16x32_bf16(aH, bL[j], acc[j], 0, 0, 0);
#pragma unroll
        for (int j = 0; j < 2; j++)
            acc[j] = __builtin_amdgcn_mfma_f32_16x16x32_bf16(aL, bH[j], acc[j], 0, 0, 0);
        __syncthreads();
    }

    {
        int mg = bm + w * 16 + ks * 4;
#pragma unroll
        for (int j = 0; j < 2; j++) {
            int ng = n0 + j * 16 + lr;
#pragma unroll
            for (int r = 0; r < 4; r++) {
                float v = acc[j][r];
                if (RESID) v += resid[(size_t)(mg + r) * 256 + ng];
                C[(size_t)(mg + r) * 256 + ng] = v;
            }
        }
    }
}

// ---------------------------------------------------------------------------
// attention core: RoPE(q) + scores -> softmax -> PV, bf16 KV.
// XCD-cluster swizzle: q = (bid&7)*256 + bid>>3.
// ---------------------------------------------------------------------------
__global__ __launch_bounds__(256) void attn_core(const float* __restrict__ qr,
                                                 const float* __restrict__ qpos,
                                                 const unsigned short* __restrict__ kv16,
                                                 const float* __restrict__ freqs,
                                                 unsigned short* __restrict__ Phi,
                                                 unsigned short* __restrict__ Plo) {
    __shared__ __align__(16) float qsh[Dd];
    __shared__ float sL[NHh * KP];
    __shared__ int   kidx[KP];
    __shared__ float attnP[8][Dd];
    __shared__ float invS[NHh];

    const int q = ((blockIdx.x & 7) << 8) | (blockIdx.x >> 3);
    const int t = threadIdx.x;
    const int h = t >> 5, lane = t & 31;

    float qx = qpos[q * 4 + 1];
    float qy = qpos[q * 4 + 2];
    int   bb = (int)qpos[q * 4 + 0];

    {
        float x = qr[q * Dd + t];
        int f = (t & 31) >> 1;
        float ang = qx * freqs[f] + qy * freqs[16 + f] + 3.0f * freqs[32 + f];
        float c = cosf(ang), sn = sinf(ang);
        float partner = __shfl_xor(x, 1);
        qsh[t] = (!(t & 1)) ? (x * c - partner * sn) : (partner * sn + x * c);
    }

    if (t < KP) {
        int k = t;
        int kv = -1;
        if (k < KK) {
            int S, base, off, sz, half, lg;
            if      (k < 9)  { S = 8;  base = 0;    off = k;      sz = 3; half = 1; lg = 3; }
            else if (k < 34) { S = 16; base = 64;   off = k - 9;  sz = 5; half = 2; lg = 4; }
            else if (k < 83) { S = 32; base = 320;  off = k - 34; sz = 7; half = 3; lg = 5; }
            else             { S = 64; base = 1344; off = k - 83; sz = 9; half = 4; lg = 6; }
            int di = off / sz - half;
            int dj = off % sz - half;
            float scal = (float)S * (1.0f / 64.0f);
            int ci = (int)floorf(qx * scal);
            int cj = (int)floorf(qy * scal);
            int i = ci + di, j = cj + dj;
            bool valid = (i >= 0) & (i < S) & (j >= 0) & (j < S);
            kv = valid ? (bb * PPB + base + (i << lg) + j) : -1;
        }
        kidx[t] = kv;
    }
    __syncthreads();

    float qreg[32];
#pragma unroll
    for (int i = 0; i < 32; i++) qreg[i] = qsh[h * HDd + i];

#pragma unroll
    for (int ct = 0; ct < 6; ++ct) {
        int k = ct * 32 + lane;
        int ki = kidx[k];
        int kr = ki < 0 ? 0 : ki;
        const ushort8* kp = (const ushort8*)(kv16 + (size_t)kr * TWO_D + h * HDd);
        float c0 = 0.f, c1 = 0.f;
#pragma unroll
        for (int s4 = 0; s4 < 4; s4++) {
            ushort8 kvv = kp[s4];
            float* cc = (s4 & 1) ? &c1 : &c0;
#pragma unroll
            for (int e = 0; e < 8; e++)
                *cc = fmaf(qreg[s4 * 8 + e], bf2f(kvv[e]), *cc);
        }
        sL[h * KP + k] = (ki >= 0) ? (c0 + c1) : -INFINITY;
    }
    __syncthreads();

    float mx = -INFINITY;
#pragma unroll
    for (int ct = 0; ct < 6; ++ct) mx = fmaxf(mx, sL[h * KP + ct * 32 + lane]);
#pragma unroll
    for (int mK = 16; mK >= 1; mK >>= 1) mx = fmaxf(mx, __shfl_xor(mx, mK));
    float se = 0.f;
#pragma unroll
    for (int ct = 0; ct < 6; ++ct) {
        int k = ct * 32 + lane;
        float e = __expf(sL[h * KP + k] - mx);
        sL[h * KP + k] = e;
        se += e;
    }
#pragma unroll
    for (int mK = 16; mK >= 1; mK >>= 1) se += __shfl_xor(se, mK);
    if (lane == 0) invS[h] = 1.0f / se;
    __syncthreads();

    {
        const int rep  = t >> 6;
        const int half = (t >> 5) & 1;
        const int l5   = t & 31;
        const int hh   = l5 >> 2;
        const int oct  = l5 & 3;
        float a[8];
#pragma unroll
        for (int e = 0; e < 8; e++) a[e] = 0.f;
        const unsigned short* vbase = kv16 + Dd + hh * HDd + oct * 8;
#pragma unroll 4
        for (int it = 0; it < 24; it++) {
            int k = rep * 48 + it * 2 + half;
            float w0 = sL[hh * KP + k];
            int kr = kidx[k]; kr = kr < 0 ? 0 : kr;
            ushort8 vv = *(const ushort8*)(vbase + (size_t)kr * TWO_D);
#pragma unroll
            for (int e = 0; e < 8; e++) a[e] = fmaf(w0, bf2f(vv[e]), a[e]);
        }
        float* dst = &attnP[t >> 5][hh * HDd + oct * 8];
#pragma unroll
        for (int e = 0; e < 8; e++) dst[e] = a[e];
    }
    __syncthreads();

    float val = 0.f;
#pragma unroll
    for (int s = 0; s < 8; s++) val += attnP[s][t];
    val *= invS[h];
    unsigned short hi = bf16_rne(val);
    Phi[q * Dd + t] = hi;
    Plo[q * Dd + t] = bf16_rne(val - bf2f(hi));
}

// ---------------------------------------------------------------------------
// Fallback: fp32 pipeline if ws too small
// ---------------------------------------------------------------------------
#define BMf 128
#define BNf 128
#define KTf 16

__global__ __launch_bounds__(256) void kv_gemm(const float* __restrict__ fmap,
                                               const float* __restrict__ Wkv,
                                               float* __restrict__ kvws) {
    __shared__ float Asf[KTf][BMf + 4];
    __shared__ float Bsf[KTf][BNf + 4];
    __shared__ int   rowOff[BMf];

    const int t  = threadIdx.x;
    const int bm = blockIdx.x * BMf;
    const int n0 = blockIdx.y * BNf;

    if (t < BMf) {
        int m = bm + t;
        int b = m / PPB;
        int r = m - b * PPB;
        int l, S, base, lg, inv;
        row_geom(r, l, S, base, lg, inv);
        int idx = r - base;
        int i = idx >> lg;
        int j = idx & (S - 1);
        rowOff[t] = ((b * 64 + i) * 64 + j) * 1024 + l * 256;
    }
    __syncthreads();

    const int tx = t & 15, ty = t >> 4;
    float acc[8][8];
#pragma unroll
    for (int i = 0; i < 8; i++)
#pragma unroll
        for (int j = 0; j < 8; j++) acc[i][j] = 0.f;

    for (int k0 = 0; k0 < Dd; k0 += KTf) {
#pragma unroll
        for (int s = 0; s < 2; s++) {
            int task = t + s * 256;
            int row  = task >> 2;
            int k4   = (task & 3) * 4;
            const float4 v = *(const float4*)(fmap + rowOff[row] + k0 + k4);
            Asf[k4 + 0][row] = v.x;
            Asf[k4 + 1][row] = v.y;
            Asf[k4 + 2][row] = v.z;
            Asf[k4 + 3][row] = v.w;
        }
#pragma unroll
        for (int s = 0; s < 2; s++) {
            int task = t + s * 256;
            int kk   = task >> 5;
            int c4   = (task & 31) * 4;
            *(float4*)(&Bsf[kk][c4]) = *(const float4*)(Wkv + (k0 + kk) * TWO_D + n0 + c4);
        }
        __syncthreads();
#pragma unroll
        for (int kk = 0; kk < KTf; kk++) {
            float a[8], bb[8];
#pragma unroll
            for (int i = 0; i < 8; i++) a[i]  = Asf[kk][ty * 8 + i];
#pragma unroll
            for (int j = 0; j < 8; j++) bb[j] = Bsf[kk][tx * 8 + j];
#pragma unroll
            for (int i = 0; i < 8; i++)
#pragma unroll
                for (int j = 0; j < 8; j++)
                    acc[i][j] = fmaf(a[i], bb[j], acc[i][j]);
        }
        __syncthreads();
    }

#pragma unroll
    for (int i = 0; i < 8; i++) {
        int m = bm + ty * 8 + i;
        float* dst = kvws + (size_t)m * TWO_D + n0 + tx * 8;
#pragma unroll
        for (int j = 0; j < 8; j += 4) {
            *(float4*)(dst + j) = make_float4(acc[i][j], acc[i][j + 1],
                                              acc[i][j + 2], acc[i][j + 3]);
        }
    }
}

__global__ __launch_bounds__(256) void rope_k_f32(float* __restrict__ kvws,
                                                  const float* __restrict__ freqs) {
    int gid = blockIdx.x * 256 + threadIdx.x;
    int m = gid >> 7;
    int p = gid & 127;
    int f = p & 15;
    int b = m / PPB;
    int r = m - b * PPB;
    int l, S, base, lg, inv;
    row_geom(r, l, S, base, lg, inv);
    int idx = r - base;
    int i = idx >> lg;
    int j = idx & (S - 1);
    float px = (float)(i * inv), py = (float)(j * inv), pl = (float)l;
    float ang = px * freqs[f] + py * freqs[16 + f] + pl * freqs[32 + f];
    float c = cosf(ang), s = sinf(ang);
    float2* kp = (float2*)kvws + (size_t)m * 256 + p;
    float2 v = *kp;
    *kp = make_float2(v.x * c - v.y * s, v.x * s + v.y * c);
}

__global__ __launch_bounds__(256) void attn_fused(const float* __restrict__ query,
                                                  const float* __restrict__ qpos,
                                                  const float* __restrict__ Wq,
                                                  const float* __restrict__ Wout,
                                                  const float* __restrict__ gamma,
                                                  const float* __restrict__ beta,
                                                  const float* __restrict__ freqs,
                                                  const float* __restrict__ kvws,
                                                  float* __restrict__ out) {
    __shared__ float qn[Dd];
    __shared__ __align__(16) float qsh[Dd];
    __shared__ float sL[NHh * KK];
    __shared__ int   kidx[KK];
    __shared__ float attnL[Dd];
    __shared__ float red[4];
    __shared__ float invS[NHh];

    const int q = blockIdx.x;
    const int t = threadIdx.x;
    const int wid = t >> 6;
    const int h = t >> 5, lane = t & 31;

    float x = query[q * Dd + t];
    float s = x;
#pragma unroll
    for (int mK = 32; mK >= 1; mK >>= 1) s += __shfl_xor(s, mK);
    if ((t & 63) == 0) red[wid] = s;
    __syncthreads();
    float mu = (red[0] + red[1] + red[2] + red[3]) * (1.0f / 256.0f);
    float dx = x - mu;
    float s2 = dx * dx;
#pragma unroll
    for (int mK = 32; mK >= 1; mK >>= 1) s2 += __shfl_xor(s2, mK);
    __syncthreads();
    if ((t & 63) == 0) red[wid] = s2;
    __syncthreads();
    float var = (red[0] + red[1] + red[2] + red[3]) * (1.0f / 256.0f);
    float rs = rsqrtf(var + 1e-5f);
    qn[t] = dx * rs * gamma[t] + beta[t];
    __syncthreads();

    float a0 = 0.f, a1 = 0.f, a2 = 0.f, a3 = 0.f;
#pragma unroll 8
    for (int d = 0; d < Dd; d += 4) {
        a0 = fmaf(qn[d + 0], Wq[(d + 0) * Dd + t], a0);
        a1 = fmaf(qn[d + 1], Wq[(d + 1) * Dd + t], a1);
        a2 = fmaf(qn[d + 2], Wq[(d + 2) * Dd + t], a2);
        a3 = fmaf(qn[d + 3], Wq[(d + 3) * Dd + t], a3);
    }
    float acc = (a0 + a1) + (a2 + a3);

    float qx = qpos[q * 4 + 1];
    float qy = qpos[q * 4 + 2];
    int   bb = (int)qpos[q * 4 + 0];
    {
        int f = (t & 31) >> 1;
        float ang = qx * freqs[f] + qy * freqs[16 + f] + 3.0f * freqs[32 + f];
        float c = cosf(ang), sn = sinf(ang);
        float partner = __shfl_xor(acc, 1);
        bool ev = !(t & 1);
        acc = ev ? (acc * c - partner * sn) : (partner * sn + acc * c);
    }
    qsh[t] = acc;

    if (t < KK) {
        int k = t;
        int S, base, off, sz, half, lg;
        if      (k < 9)  { S = 8;  base = 0;    off = k;      sz = 3; half = 1; lg = 3; }
        else if (k < 34) { S = 16; base = 64;   off = k - 9;  sz = 5; half = 2; lg = 4; }
        else if (k < 83) { S = 32; base = 320;  off = k - 34; sz = 7; half = 3; lg = 5; }
        else             { S = 64; base = 1344; off = k - 83; sz = 9; half = 4; lg = 6; }
        int di = off / sz - half;
        int dj = off % sz - half;
        float scal = (float)S * (1.0f / 64.0f);
        int ci = (int)floorf(qx * scal);
        int cj = (int)floorf(qy * scal);
        int i = ci + di, j = cj + dj;
        bool valid = (i >= 0) & (i < S) & (j >= 0) & (j < S);
        kidx[t] = valid ? (bb * PPB + base + (i << lg) + j) : -1;
    }
    __syncthreads();

    float4 qv[8];
    {
        const float4* qp = (const float4*)(qsh + h * HDd);
#pragma unroll
        for (int i = 0; i < 8; i++) qv[i] = qp[i];
    }
#pragma unroll
    for (int ct = 0; ct < 6; ++ct) {
        int k = ct * 32 + lane;
        if (k >= KK) break;
        int ki = kidx[k];
        int kr = ki < 0 ? 0 : ki;
        const float4* kp = (const float4*)(kvws + (size_t)kr * TWO_D + h * HDd);
        float c0 = 0.f, c1 = 0.f;
#pragma unroll
        for (int i = 0; i < 8; i += 2) {
            float4 k0v = kp[i], k1v = kp[i + 1];
            c0 = fmaf(qv[i].x, k0v.x, c0); c0 = fmaf(qv[i].y, k0v.y, c0);
            c0 = fmaf(qv[i].z, k0v.z, c0); c0 = fmaf(qv[i].w, k0v.w, c0);
            c1 = fmaf(qv[i + 1].x, k1v.x, c1); c1 = fmaf(qv[i + 1].y, k1v.y, c1);
            c1 = fmaf(qv[i + 1].z, k1v.z, c1); c1 = fmaf(qv[i + 1].w, k1v.w, c1);
        }
        sL[h * KK + k] = (ki >= 0) ? (c0 + c1) : -INFINITY;
    }
    __syncthreads();

    float mx = -INFINITY;
    for (int k = lane; k < KK; k += 32) mx = fmaxf(mx, sL[h * KK + k]);
#pragma unroll
    for (int mK = 16; mK >= 1; mK >>= 1) mx = fmaxf(mx, __shfl_xor(mx, mK));
    float se = 0.f;
    for (int k = lane; k < KK; k += 32) {
        float e = expf(sL[h * KK + k] - mx);
        sL[h * KK + k] = e;
        se += e;
    }
#pragma unroll
    for (int mK = 16; mK >= 1; mK >>= 1) se += __shfl_xor(se, mK);
    if (lane == 0) invS[h] = 1.0f / se;
    __syncthreads();

    float p0 = 0.f, p1 = 0.f, p2 = 0.f, p3 = 0.f;
#pragma unroll 4
    for (int k = 0; k < 164; k += 4) {
        int ki0 = kidx[k],     kr0 = ki0 < 0 ? 0 : ki0;
        int ki1 = kidx[k + 1], kr1 = ki1 < 0 ? 0 : ki1;
        int ki2 = kidx[k + 2], kr2 = ki2 < 0 ? 0 : ki2;
        int ki3 = kidx[k + 3], kr3 = ki3 < 0 ? 0 : ki3;
        p0 = fmaf(sL[h * KK + k],     kvws[(size_t)kr0 * TWO_D + Dd + t], p0);
        p1 = fmaf(sL[h * KK + k + 1], kvws[(size_t)kr1 * TWO_D + Dd + t], p1);
        p2 = fmaf(sL[h * KK + k + 2], kvws[(size_t)kr2 * TWO_D + Dd + t], p2);
        p3 = fmaf(sL[h * KK + k + 3], kvws[(size_t)kr3 * TWO_D + Dd + t], p3);
    }
    attnL[t] = ((p0 + p1) + (p2 + p3)) * invS[h];
    __syncthreads();

    float o0 = query[q * Dd + t], o1 = 0.f, o2 = 0.f, o3 = 0.f;
#pragma unroll 8
    for (int d = 0; d < Dd; d += 4) {
        o0 = fmaf(attnL[d + 0], Wout[(d + 0) * Dd + t], o0);
        o1 = fmaf(attnL[d + 1], Wout[(d + 1) * Dd + t], o1);
        o2 = fmaf(attnL[d + 2], Wout[(d + 2) * Dd + t], o2);
        o3 = fmaf(attnL[d + 3], Wout[(d + 3) * Dd + t], o3);
    }
    out[q * Dd + t] = (o0 + o1) + (o2 + o3);
}

// ---------------------------------------------------------------------------
extern "C" void kernel_launch(void* const* d_in, const int* in_sizes, int n_in,
                              void* d_out, int out_size, void* d_ws, size_t ws_size,
                              hipStream_t stream) {
    const float* query = (const float*)d_in[0];
    const float* qpos  = (const float*)d_in[1];
    const float* fmap  = (const float*)d_in[3];
    const float* gamma = (const float*)d_in[5];
    const float* beta  = (const float*)d_in[6];
    const float* Wq    = (const float*)d_in[7];
    const float* Wkv   = (const float*)d_in[8];
    const float* Wout  = (const float*)d_in[9];
    const float* freqs = (const float*)d_in[10];
    float* out = (float*)d_out;

    // flat workspace layout
    const size_t O_KV16   = 0;            // 22,282,240
    const size_t O_AHI    = 22282240;     // 11,141,120
    const size_t O_ALO    = 33423360;     // 11,141,120
    const size_t O_WKVHI  = 44564480;     //    262,144
    const size_t O_WKVLO  = 44826624;     //    262,144
    const size_t O_WQHI   = 45088768;     //    131,072
    const size_t O_WQLO   = 45219840;     //    131,072
    const size_t O_WOHI   = 45350912;     //    131,072
    const size_t O_WOLO   = 45481984;     //    131,072
    const size_t O_XHI    = 45613056;     //  1,048,576
    const size_t O_XLO    = 46661632;     //  1,048,576
    const size_t O_QR     = 47710208;     //  2,097,152
    const size_t O_PHI    = 49807360;     //  1,048,576
    const size_t O_PLO    = 50855936;     //  1,048,576
    const size_t need     = 51904512;

    if (ws_size >= need) {
        char* base = (char*)d_ws;
        unsigned short* kv16   = (unsigned short*)(base + O_KV16);
        unsigned short* Ahi    = (unsigned short*)(base + O_AHI);
        unsigned short* Alo    = (unsigned short*)(base + O_ALO);
        unsigned short* WkvThi = (unsigned short*)(base + O_WKVHI);
        unsigned short* WkvTlo = (unsigned short*)(base + O_WKVLO);
        unsigned short* WqThi  = (unsigned short*)(base + O_WQHI);
        unsigned short* WqTlo  = (unsigned short*)(base + O_WQLO);
        unsigned short* WoThi  = (unsigned short*)(base + O_WOHI);
        unsigned short* WoTlo  = (unsigned short*)(base + O_WOLO);
        unsigned short* Xhi    = (unsigned short*)(base + O_XHI);
        unsigned short* Xlo    = (unsigned short*)(base + O_XLO);
        float*          qrw    = (float*)        (base + O_QR);
        unsigned short* Phi    = (unsigned short*)(base + O_PHI);
        unsigned short* Plo    = (unsigned short*)(base + O_PLO);

        prep<<<dim3(8512), 256, 0, stream>>>(fmap, Wkv, Wq, Wout, query, gamma, beta,
                                             Ahi, Alo, WkvThi, WkvTlo,
                                             WqThi, WqTlo, WoThi, WoTlo, Xhi, Xlo);
        // 704 = 22 groups x 32; blocks with my>=170 exit early (24 blocks)
        kv_gemm_mfma<<<dim3(704), 256, 0, stream>>>(Ahi, Alo, WkvThi, WkvTlo,
                                                    freqs, kv16);
        proj_gemm<false><<<dim3(8, 32), 256, 0, stream>>>(Xhi, Xlo, WqThi, WqTlo,
                                                          qrw, nullptr);
        attn_core<<<dim3(NQ), 256, 0, stream>>>(qrw, qpos, kv16, freqs, Phi, Plo);
        proj_gemm<true><<<dim3(8, 32), 256, 0, stream>>>(Phi, Plo, WoThi, WoTlo,
                                                         out, query);
    } else {
        float* kvws = (float*)d_ws;
        kv_gemm<<<dim3(M_TOT / BMf, TWO_D / BNf), 256, 0, stream>>>(fmap, Wkv, kvws);
        rope_k_f32<<<dim3((M_TOT * 128) / 256), 256, 0, stream>>>(kvws, freqs);
        attn_fused<<<dim3(NQ), 256, 0, stream>>>(query, qpos, Wq, Wout, gamma, beta,
                                                 freqs, kvws, out);
    }
}

// Round 13
// 192.765 us; speedup vs baseline: 1.4735x; 1.0264x over previous
//
#include <hip/hip_runtime.h>
#include <math.h>

// Problem constants (fixed by reference setup_inputs)
#define NQ    2048      // B*QB
#define Dd    256
#define NHh   8
#define HDd   32
#define KK    164       // 9+25+49+81
#define KP    192       // padded K (6 full 32-tiles)
#define PPB   5440      // valid cells per batch: 64+256+1024+4096
#define M_TOT 21760     // 4 * PPB
#define TWO_D 512

using bf16x8  = __attribute__((ext_vector_type(8))) short;
using f32x4   = __attribute__((ext_vector_type(4))) float;
using ushort8 = __attribute__((ext_vector_type(8))) unsigned short;

__device__ __forceinline__ unsigned short bf16_rne(float x) {
    unsigned u = __float_as_uint(x);
    return (unsigned short)((u + 0x7fffu + ((u >> 16) & 1u)) >> 16);
}
__device__ __forceinline__ float bf2f(unsigned short h) {
    return __uint_as_float((unsigned)h << 16);
}

__device__ __forceinline__ void gload_lds16(const void* g, void* s) {
    __builtin_amdgcn_global_load_lds(
        (const __attribute__((address_space(1))) void*)g,
        (__attribute__((address_space(3))) void*)s, 16, 0, 0);
}

__device__ __forceinline__ void row_geom(int r, int& l, int& S, int& base, int& lg, int& inv) {
    if      (r < 64)   { l = 0; S = 8;  base = 0;    lg = 3; inv = 8; }
    else if (r < 320)  { l = 1; S = 16; base = 64;   lg = 4; inv = 4; }
    else if (r < 1344) { l = 2; S = 32; base = 320;  lg = 5; inv = 2; }
    else               { l = 3; S = 64; base = 1344; lg = 6; inv = 1; }
}

__device__ __forceinline__ void split8(const float4& a, const float4& b,
                                       ushort8& hi, ushort8& lo) {
    float x[8] = {a.x, a.y, a.z, a.w, b.x, b.y, b.z, b.w};
#pragma unroll
    for (int e = 0; e < 8; e++) {
        unsigned short h = bf16_rne(x[e]);
        hi[e] = h;
        lo[e] = bf16_rne(x[e] - bf2f(h));
    }
}

// ---------------------------------------------------------------------------
// prep (fused, no fmap gather anymore): blocks [0,512) split Wkv;
// [512,768) split Wq; [768,1024) split Wout; [1024,3072) LN+split query.
// ---------------------------------------------------------------------------
__device__ __forceinline__ void split_one(const float* __restrict__ W,
                                          unsigned short* __restrict__ hi_,
                                          unsigned short* __restrict__ lo_,
                                          int N, int gid) {
    int k = gid & 255, n = gid >> 8;
    float x = W[k * N + n];
    unsigned short h = bf16_rne(x);
    hi_[n * 256 + k] = h;
    lo_[n * 256 + k] = bf16_rne(x - bf2f(h));
}

__global__ __launch_bounds__(256) void prep(const float* __restrict__ Wkv,
                                            const float* __restrict__ Wq,
                                            const float* __restrict__ Wout,
                                            const float* __restrict__ query,
                                            const float* __restrict__ gamma,
                                            const float* __restrict__ beta,
                                            unsigned short* __restrict__ WkvThi,
                                            unsigned short* __restrict__ WkvTlo,
                                            unsigned short* __restrict__ WqThi,
                                            unsigned short* __restrict__ WqTlo,
                                            unsigned short* __restrict__ WoThi,
                                            unsigned short* __restrict__ WoTlo,
                                            unsigned short* __restrict__ Xhi,
                                            unsigned short* __restrict__ Xlo) {
    __shared__ float red[4];
    const int bid = blockIdx.x, t = threadIdx.x;

    if (bid < 512) {
        split_one(Wkv, WkvThi, WkvTlo, 512, bid * 256 + t);
    } else if (bid < 768) {
        split_one(Wq, WqThi, WqTlo, 256, (bid - 512) * 256 + t);
    } else if (bid < 1024) {
        split_one(Wout, WoThi, WoTlo, 256, (bid - 768) * 256 + t);
    } else {
        const int q = bid - 1024, wid = t >> 6;
        float x = query[q * Dd + t];
        float s = x;
#pragma unroll
        for (int mK = 32; mK >= 1; mK >>= 1) s += __shfl_xor(s, mK);
        if ((t & 63) == 0) red[wid] = s;
        __syncthreads();
        float mu = (red[0] + red[1] + red[2] + red[3]) * (1.0f / 256.0f);
        float dx = x - mu;
        float s2 = dx * dx;
#pragma unroll
        for (int mK = 32; mK >= 1; mK >>= 1) s2 += __shfl_xor(s2, mK);
        __syncthreads();
        if ((t & 63) == 0) red[wid] = s2;
        __syncthreads();
        float var = (red[0] + red[1] + red[2] + red[3]) * (1.0f / 256.0f);
        float v = dx * rsqrtf(var + 1e-5f) * gamma[t] + beta[t];
        unsigned short hi = bf16_rne(v);
        Xhi[q * Dd + t] = hi;
        Xlo[q * Dd + t] = bf16_rne(v - bf2f(hi));
    }
}

// ---------------------------------------------------------------------------
// Fused kvq kernel:
//   bid <  704 : KV = gather(fmap) @ Wkv, split-bf16 MFMA, co-staged 3-combo.
//                A is reg-staged DIRECTLY from fmap (gather + hi/lo split
//                in-register, swizzled ds_write) — no Ahi/Alo round-trip.
//                B via global_load_lds. 8 K-iterations, 48 MFMAs/barrier.
//                XCD-grouped swizzle; RoPE fused in epilogue (__sincosf).
//   bid >= 704 : proj_q = X @ Wq (256 blocks) — rides the kv tail.
// ---------------------------------------------------------------------------
__global__ __launch_bounds__(256) void kvq_gemm(const float* __restrict__ fmap,
                                                const unsigned short* __restrict__ Bthi,
                                                const unsigned short* __restrict__ Btlo,
                                                const unsigned short* __restrict__ Xhi,
                                                const unsigned short* __restrict__ Xlo,
                                                const unsigned short* __restrict__ WqThi,
                                                const unsigned short* __restrict__ WqTlo,
                                                const float* __restrict__ freqs,
                                                unsigned short* __restrict__ kv16,
                                                float* __restrict__ qrw) {
    __shared__ __align__(16) char smem[66048];   // 64KB panels + 512B rofs

    const int bid = blockIdx.x;
    const int t = threadIdx.x;
    const int w = t >> 6, l = t & 63;
    const int lr = l & 15, ks = l >> 4;
    const int ksw8 = ((ks ^ ((lr >> 1) & 3)) << 3);
    const int srow = l >> 2, sslot = l & 3;
    const int gs = sslot ^ ((srow >> 1) & 3);

    if (bid < 704) {
        // ---------------- KV GEMM path ----------------
        const int my = (bid >> 5) * 8 + (bid & 7);
        const int mx = (bid >> 3) & 3;
        if (my >= 170) return;

        const int wr = w >> 1, wc = w & 1;
        const int n0 = mx * 128, bm = my * 128;
        const bool doRope = (n0 < 256);

        short* AsB = (short*)smem;                       // [2][2][4096]
        short* BsB = (short*)(smem + 32768);             // [2][2][4096]
        int*   rofs = (int*)(smem + 65536);              // [128]
        auto ASP = [&](int buf, int sel) { return AsB + (buf * 2 + sel) * 4096; };
        auto BSP = [&](int buf, int sel) { return BsB + (buf * 2 + sel) * 4096; };

        if (t < 128) {
            int m = bm + t;
            int b = m / PPB, r = m - b * PPB;
            int lL, S, base, lg, inv;
            row_geom(r, lL, S, base, lg, inv);
            int idx = r - base;
            rofs[t] = ((b * 64 + (idx >> lg)) * 64 + (idx & (S - 1))) * 1024 + lL * 256;
        }
        __syncthreads();

        f32x4 acc[4][4];
#pragma unroll
        for (int i = 0; i < 4; i++)
#pragma unroll
            for (int j = 0; j < 4; j++) { f32x4 z = {0.f,0.f,0.f,0.f}; acc[i][j] = z; }

        // A: reg-staged gather+split from fmap; writes swizzled slots so that
        // LDS slot s of row m holds global k-slot s ^ ((m>>1)&3) (read-compatible).
        auto stageA = [&](int kt, int buf) {
            const int row = t >> 1;
            const int kh  = (t & 1) << 4;
            const float* src = fmap + rofs[row] + (kt << 5) + kh;
            float4 v0 = *(const float4*)(src);
            float4 v1 = *(const float4*)(src + 4);
            float4 v2 = *(const float4*)(src + 8);
            float4 v3 = *(const float4*)(src + 12);
            ushort8 h0, l0, h1, l1;
            split8(v0, v1, h0, l0);
            split8(v2, v3, h1, l1);
            const int sw = (row >> 1) & 3;
            const int s0 = kh >> 3;              // 0 or 2
            short* ah = ASP(buf, 0) + row * 32;
            short* al = ASP(buf, 1) + row * 32;
            *(ushort8*)(ah + ((s0 ^ sw) << 3))       = h0;
            *(ushort8*)(ah + (((s0 + 1) ^ sw) << 3)) = h1;
            *(ushort8*)(al + ((s0 ^ sw) << 3))       = l0;
            *(ushort8*)(al + (((s0 + 1) ^ sw) << 3)) = l1;
        };
        auto stageB = [&](int kt, int buf) {
            size_t k0b = (size_t)(kt << 6);
#pragma unroll
            for (int i = 0; i < 2; i++) {
                int rb = w * 32 + i * 16;
                int m  = rb + srow;
                size_t bofs = (((size_t)(n0 + m)) << 9) + k0b + (gs << 4);
                gload_lds16((const char*)Bthi + bofs, (void*)(BSP(buf, 0) + rb * 32));
                gload_lds16((const char*)Btlo + bofs, (void*)(BSP(buf, 1) + rb * 32));
            }
        };

        stageA(0, 0);
        stageB(0, 0);
        __syncthreads();

        for (int kt = 0; kt < 8; kt++) {
            int cur = kt & 1;
            if (kt < 7) {
                stageA(kt + 1, cur ^ 1);
                stageB(kt + 1, cur ^ 1);
            }

            bf16x8 aH[4], aL[4], bH[4], bL[4];
#pragma unroll
            for (int f = 0; f < 4; f++) {
                int m = wr * 64 + f * 16 + lr;
                aH[f] = *(const bf16x8*)(ASP(cur, 0) + m * 32 + ksw8);
                aL[f] = *(const bf16x8*)(ASP(cur, 1) + m * 32 + ksw8);
                int n = wc * 64 + f * 16 + lr;
                bH[f] = *(const bf16x8*)(BSP(cur, 0) + n * 32 + ksw8);
                bL[f] = *(const bf16x8*)(BSP(cur, 1) + n * 32 + ksw8);
            }
#pragma unroll
            for (int i = 0; i < 4; i++)
#pragma unroll
                for (int j = 0; j < 4; j++)
                    acc[i][j] = __builtin_amdgcn_mfma_f32_16x16x32_bf16(aH[i], bH[j],
                                                                        acc[i][j], 0, 0, 0);
#pragma unroll
            for (int i = 0; i < 4; i++)
#pragma unroll
                for (int j = 0; j < 4; j++)
                    acc[i][j] = __builtin_amdgcn_mfma_f32_16x16x32_bf16(aH[i], bL[j],
                                                                        acc[i][j], 0, 0, 0);
#pragma unroll
            for (int i = 0; i < 4; i++)
#pragma unroll
                for (int j = 0; j < 4; j++)
                    acc[i][j] = __builtin_amdgcn_mfma_f32_16x16x32_bf16(aL[i], bH[j],
                                                                        acc[i][j], 0, 0, 0);
            __syncthreads();
        }

        // epilogue: C/D layout col = lane&15, row = (lane>>4)*4 + reg.
        float fx0 = 0.f, fy0 = 0.f, fz0 = 0.f, fx1 = 0.f, fy1 = 0.f, fz1 = 0.f;
        if (doRope) {
            int e0 = lr >> 1, e1 = e0 + 8;
            fx0 = freqs[e0]; fy0 = freqs[16 + e0]; fz0 = freqs[32 + e0];
            fx1 = freqs[e1]; fy1 = freqs[16 + e1]; fz1 = freqs[32 + e1];
        }
#pragma unroll
        for (int i = 0; i < 4; i++) {
            int mg = bm + wr * 64 + i * 16 + ks * 4;
#pragma unroll
            for (int r = 0; r < 4; r++) {
                int m = mg + r;
                float c0 = 1.f, s0 = 0.f, c1 = 1.f, s1 = 0.f;
                if (doRope) {
                    int b = m / PPB;
                    int rw = m - b * PPB;
                    int lL, S, base, lg, inv;
                    row_geom(rw, lL, S, base, lg, inv);
                    int idx = rw - base;
                    float px = (float)((idx >> lg) * inv);
                    float py = (float)((idx & (S - 1)) * inv);
                    float pl = (float)lL;
                    __sincosf(px * fx0 + py * fy0 + pl * fz0, &s0, &c0);
                    __sincosf(px * fx1 + py * fy1 + pl * fz1, &s1, &c1);
                }
#pragma unroll
                for (int j = 0; j < 4; j++) {
                    int ng = n0 + wc * 64 + j * 16 + lr;
                    float self = acc[i][j][r];
                    float part = __shfl_xor(self, 1);
                    if (!(lr & 1)) {
                        float y1 = self, y2 = part;
                        if (doRope) {
                            float c = (j & 1) ? c1 : c0;
                            float s = (j & 1) ? s1 : s0;
                            y1 = self * c - part * s;
                            y2 = self * s + part * c;
                        }
                        unsigned word = (unsigned)bf16_rne(y1) | ((unsigned)bf16_rne(y2) << 16);
                        *(unsigned*)(kv16 + (size_t)m * TWO_D + ng) = word;
                    }
                }
            }
        }
    } else {
        // ---------------- proj_q path (X @ Wq -> qrw) ----------------
        const int pbid = bid - 704;
        const int n0 = (pbid & 7) * 32, bm = (pbid >> 3) * 64;

        short* AsB = (short*)smem;                       // [2][2][2048] = 16KB
        short* BsB = (short*)(smem + 16384);             // [2][2][1024] = 8KB
        auto ASQ = [&](int buf, int sel) { return AsB + (buf * 2 + sel) * 2048; };
        auto BSQ = [&](int buf, int sel) { return BsB + (buf * 2 + sel) * 1024; };

        f32x4 acc[2];
#pragma unroll
        for (int j = 0; j < 2; j++) { f32x4 z = {0.f,0.f,0.f,0.f}; acc[j] = z; }

        auto stage = [&](int kt, int buf) {
            size_t k0b = (size_t)(kt << 6);
            {
                int rb = w * 16;
                int m  = rb + srow;
                size_t aofs = (((size_t)(bm + m)) << 9) + k0b + (gs << 4);
                gload_lds16((const char*)Xhi + aofs, (void*)(ASQ(buf, 0) + rb * 32));
                gload_lds16((const char*)Xlo + aofs, (void*)(ASQ(buf, 1) + rb * 32));
            }
            {
                int sel = w >> 1;
                int rb  = (w & 1) * 16;
                int m   = rb + srow;
                const unsigned short* Bp = sel ? WqTlo : WqThi;
                size_t bofs = (((size_t)(n0 + m)) << 9) + k0b + (gs << 4);
                gload_lds16((const char*)Bp + bofs, (void*)(BSQ(buf, sel) + rb * 32));
            }
        };

        stage(0, 0);
        __syncthreads();

        for (int kt = 0; kt < 8; kt++) {
            int cur = kt & 1;
            if (kt < 7) stage(kt + 1, cur ^ 1);

            bf16x8 aH, aL, bH[2], bL[2];
            {
                int m = w * 16 + lr;
                aH = *(const bf16x8*)(ASQ(cur, 0) + m * 32 + ksw8);
                aL = *(const bf16x8*)(ASQ(cur, 1) + m * 32 + ksw8);
            }
#pragma unroll
            for (int j = 0; j < 2; j++) {
                int n = j * 16 + lr;
                bH[j] = *(const bf16x8*)(BSQ(cur, 0) + n * 32 + ksw8);
                bL[j] = *(const bf16x8*)(BSQ(cur, 1) + n * 32 + ksw8);
            }
#pragma unroll
            for (int j = 0; j < 2; j++)
                acc[j] = __builtin_amdgcn_mfma_f32_16x16x32_bf16(aH, bH[j], acc[j], 0, 0, 0);
#pragma unroll
            for (int j = 0; j < 2; j++)
                acc[j] = __builtin_amdgcn_mfma_f32_16x16x32_bf16(aH, bL[j], acc[j], 0, 0, 0);
#pragma unroll
            for (int j = 0; j < 2; j++)
                acc[j] = __builtin_amdgcn_mfma_f32_16x16x32_bf16(aL, bH[j], acc[j], 0, 0, 0);
            __syncthreads();
        }

        {
            int mg = bm + w * 16 + ks * 4;
#pragma unroll
            for (int j = 0; j < 2; j++) {
                int ng = n0 + j * 16 + lr;
#pragma unroll
                for (int r = 0; r < 4; r++)
                    qrw[(size_t)(mg + r) * 256 + ng] = acc[j][r];
            }
        }
    }
}

// ---------------------------------------------------------------------------
// out-proj GEMM, co-staged 3-combo: out = P @ Wout + query. grid (8,32).
// ---------------------------------------------------------------------------
__global__ __launch_bounds__(256) void proj_out(const unsigned short* __restrict__ Ahi,
                                                const unsigned short* __restrict__ Alo,
                                                const unsigned short* __restrict__ Bthi,
                                                const unsigned short* __restrict__ Btlo,
                                                float* __restrict__ C,
                                                const float* __restrict__ resid) {
    __shared__ __align__(16) short As[2][2][64 * 32];
    __shared__ __align__(16) short Bs[2][2][32 * 32];

    const int t  = threadIdx.x;
    const int w  = t >> 6, l = t & 63;
    const int n0 = blockIdx.x * 32, bm = blockIdx.y * 64;
    const int lr = l & 15, ks = l >> 4;
    const int ksw8 = ((ks ^ ((lr >> 1) & 3)) << 3);

    f32x4 acc[2];
#pragma unroll
    for (int j = 0; j < 2; j++) { f32x4 z = {0.f,0.f,0.f,0.f}; acc[j] = z; }

    const int srow = l >> 2, sslot = l & 3;
    const int gs = sslot ^ ((srow >> 1) & 3);

    auto stage = [&](int kt, int buf) {
        size_t k0b = (size_t)(kt << 6);
        {
            int rb = w * 16;
            int m  = rb + srow;
            size_t aofs = (((size_t)(bm + m)) << 9) + k0b + (gs << 4);
            gload_lds16((const char*)Ahi + aofs, (void*)&As[buf][0][rb * 32]);
            gload_lds16((const char*)Alo + aofs, (void*)&As[buf][1][rb * 32]);
        }
        {
            int sel = w >> 1;
            int rb  = (w & 1) * 16;
            int m   = rb + srow;
            const unsigned short* Bp = sel ? Btlo : Bthi;
            size_t bofs = (((size_t)(n0 + m)) << 9) + k0b + (gs << 4);
            gload_lds16((const char*)Bp + bofs, (void*)&Bs[buf][sel][rb * 32]);
        }
    };

    stage(0, 0);
    __syncthreads();

    for (int kt = 0; kt < 8; kt++) {
        int cur = kt & 1;
        if (kt < 7) stage(kt + 1, cur ^ 1);

        bf16x8 aH, aL, bH[2], bL[2];
        {
            int m = w * 16 + lr;
            aH = *(const bf16x8*)&As[cur][0][m * 32 + ksw8];
            aL = *(const bf16x8*)&As[cur][1][m * 32 + ksw8];
        }
#pragma unroll
        for (int j = 0; j < 2; j++) {
            int n = j * 16 + lr;
            bH[j] = *(const bf16x8*)&Bs[cur][0][n * 32 + ksw8];
            bL[j] = *(const bf16x8*)&Bs[cur][1][n * 32 + ksw8];
        }
#pragma unroll
        for (int j = 0; j < 2; j++)
            acc[j] = __builtin_amdgcn_mfma_f32_16x16x32_bf16(aH, bH[j], acc[j], 0, 0, 0);
#pragma unroll
        for (int j = 0; j < 2; j++)
            acc[j] = __builtin_amdgcn_mfma_f32_16x16x32_bf16(aH, bL[j], acc[j], 0, 0, 0);
#pragma unroll
        for (int j = 0; j < 2; j++)
            acc[j] = __builtin_amdgcn_mfma_f32_16x16x32_bf16(aL, bH[j], acc[j], 0, 0, 0);
        __syncthreads();
    }

    {
        int mg = bm + w * 16 + ks * 4;
#pragma unroll
        for (int j = 0; j < 2; j++) {
            int ng = n0 + j * 16 + lr;
#pragma unroll
            for (int r = 0; r < 4; r++)
                C[(size_t)(mg + r) * 256 + ng] = acc[j][r] + resid[(size_t)(mg + r) * 256 + ng];
        }
    }
}

// ---------------------------------------------------------------------------
// attention core: RoPE(q) + scores -> softmax -> PV, bf16 KV.
// XCD-cluster swizzle: q = (bid&7)*256 + bid>>3.
// ---------------------------------------------------------------------------
__global__ __launch_bounds__(256) void attn_core(const float* __restrict__ qr,
                                                 const float* __restrict__ qpos,
                                                 const unsigned short* __restrict__ kv16,
                                                 const float* __restrict__ freqs,
                                                 unsigned short* __restrict__ Phi,
                                                 unsigned short* __restrict__ Plo) {
    __shared__ __align__(16) float qsh[Dd];
    __shared__ float sL[NHh * KP];
    __shared__ int   kidx[KP];
    __shared__ float attnP[8][Dd];
    __shared__ float invS[NHh];

    const int q = ((blockIdx.x & 7) << 8) | (blockIdx.x >> 3);
    const int t = threadIdx.x;
    const int h = t >> 5, lane = t & 31;

    float qx = qpos[q * 4 + 1];
    float qy = qpos[q * 4 + 2];
    int   bb = (int)qpos[q * 4 + 0];

    {
        float x = qr[q * Dd + t];
        int f = (t & 31) >> 1;
        float ang = qx * freqs[f] + qy * freqs[16 + f] + 3.0f * freqs[32 + f];
        float c = cosf(ang), sn = sinf(ang);
        float partner = __shfl_xor(x, 1);
        qsh[t] = (!(t & 1)) ? (x * c - partner * sn) : (partner * sn + x * c);
    }

    if (t < KP) {
        int k = t;
        int kv = -1;
        if (k < KK) {
            int S, base, off, sz, half, lg;
            if      (k < 9)  { S = 8;  base = 0;    off = k;      sz = 3; half = 1; lg = 3; }
            else if (k < 34) { S = 16; base = 64;   off = k - 9;  sz = 5; half = 2; lg = 4; }
            else if (k < 83) { S = 32; base = 320;  off = k - 34; sz = 7; half = 3; lg = 5; }
            else             { S = 64; base = 1344; off = k - 83; sz = 9; half = 4; lg = 6; }
            int di = off / sz - half;
            int dj = off % sz - half;
            float scal = (float)S * (1.0f / 64.0f);
            int ci = (int)floorf(qx * scal);
            int cj = (int)floorf(qy * scal);
            int i = ci + di, j = cj + dj;
            bool valid = (i >= 0) & (i < S) & (j >= 0) & (j < S);
            kv = valid ? (bb * PPB + base + (i << lg) + j) : -1;
        }
        kidx[t] = kv;
    }
    __syncthreads();

    float qreg[32];
#pragma unroll
    for (int i = 0; i < 32; i++) qreg[i] = qsh[h * HDd + i];

#pragma unroll
    for (int ct = 0; ct < 6; ++ct) {
        int k = ct * 32 + lane;
        int ki = kidx[k];
        int kr = ki < 0 ? 0 : ki;
        const ushort8* kp = (const ushort8*)(kv16 + (size_t)kr * TWO_D + h * HDd);
        float c0 = 0.f, c1 = 0.f;
#pragma unroll
        for (int s4 = 0; s4 < 4; s4++) {
            ushort8 kvv = kp[s4];
            float* cc = (s4 & 1) ? &c1 : &c0;
#pragma unroll
            for (int e = 0; e < 8; e++)
                *cc = fmaf(qreg[s4 * 8 + e], bf2f(kvv[e]), *cc);
        }
        sL[h * KP + k] = (ki >= 0) ? (c0 + c1) : -INFINITY;
    }
    __syncthreads();

    float mx = -INFINITY;
#pragma unroll
    for (int ct = 0; ct < 6; ++ct) mx = fmaxf(mx, sL[h * KP + ct * 32 + lane]);
#pragma unroll
    for (int mK = 16; mK >= 1; mK >>= 1) mx = fmaxf(mx, __shfl_xor(mx, mK));
    float se = 0.f;
#pragma unroll
    for (int ct = 0; ct < 6; ++ct) {
        int k = ct * 32 + lane;
        float e = __expf(sL[h * KP + k] - mx);
        sL[h * KP + k] = e;
        se += e;
    }
#pragma unroll
    for (int mK = 16; mK >= 1; mK >>= 1) se += __shfl_xor(se, mK);
    if (lane == 0) invS[h] = 1.0f / se;
    __syncthreads();

    {
        const int rep  = t >> 6;
        const int half = (t >> 5) & 1;
        const int l5   = t & 31;
        const int hh   = l5 >> 2;
        const int oct  = l5 & 3;
        float a[8];
#pragma unroll
        for (int e = 0; e < 8; e++) a[e] = 0.f;
        const unsigned short* vbase = kv16 + Dd + hh * HDd + oct * 8;
#pragma unroll 4
        for (int it = 0; it < 24; it++) {
            int k = rep * 48 + it * 2 + half;
            float w0 = sL[hh * KP + k];
            int kr = kidx[k]; kr = kr < 0 ? 0 : kr;
            ushort8 vv = *(const ushort8*)(vbase + (size_t)kr * TWO_D);
#pragma unroll
            for (int e = 0; e < 8; e++) a[e] = fmaf(w0, bf2f(vv[e]), a[e]);
        }
        float* dst = &attnP[t >> 5][hh * HDd + oct * 8];
#pragma unroll
        for (int e = 0; e < 8; e++) dst[e] = a[e];
    }
    __syncthreads();

    float val = 0.f;
#pragma unroll
    for (int s = 0; s < 8; s++) val += attnP[s][t];
    val *= invS[h];
    unsigned short hi = bf16_rne(val);
    Phi[q * Dd + t] = hi;
    Plo[q * Dd + t] = bf16_rne(val - bf2f(hi));
}

// ---------------------------------------------------------------------------
// Fallback: fp32 pipeline if ws too small
// ---------------------------------------------------------------------------
#define BMf 128
#define BNf 128
#define KTf 16

__global__ __launch_bounds__(256) void kv_gemm(const float* __restrict__ fmap,
                                               const float* __restrict__ Wkv,
                                               float* __restrict__ kvws) {
    __shared__ float Asf[KTf][BMf + 4];
    __shared__ float Bsf[KTf][BNf + 4];
    __shared__ int   rowOff[BMf];

    const int t  = threadIdx.x;
    const int bm = blockIdx.x * BMf;
    const int n0 = blockIdx.y * BNf;

    if (t < BMf) {
        int m = bm + t;
        int b = m / PPB;
        int r = m - b * PPB;
        int l, S, base, lg, inv;
        row_geom(r, l, S, base, lg, inv);
        int idx = r - base;
        int i = idx >> lg;
        int j = idx & (S - 1);
        rowOff[t] = ((b * 64 + i) * 64 + j) * 1024 + l * 256;
    }
    __syncthreads();

    const int tx = t & 15, ty = t >> 4;
    float acc[8][8];
#pragma unroll
    for (int i = 0; i < 8; i++)
#pragma unroll
        for (int j = 0; j < 8; j++) acc[i][j] = 0.f;

    for (int k0 = 0; k0 < Dd; k0 += KTf) {
#pragma unroll
        for (int s = 0; s < 2; s++) {
            int task = t + s * 256;
            int row  = task >> 2;
            int k4   = (task & 3) * 4;
            const float4 v = *(const float4*)(fmap + rowOff[row] + k0 + k4);
            Asf[k4 + 0][row] = v.x;
            Asf[k4 + 1][row] = v.y;
            Asf[k4 + 2][row] = v.z;
            Asf[k4 + 3][row] = v.w;
        }
#pragma unroll
        for (int s = 0; s < 2; s++) {
            int task = t + s * 256;
            int kk   = task >> 5;
            int c4   = (task & 31) * 4;
            *(float4*)(&Bsf[kk][c4]) = *(const float4*)(Wkv + (k0 + kk) * TWO_D + n0 + c4);
        }
        __syncthreads();
#pragma unroll
        for (int kk = 0; kk < KTf; kk++) {
            float a[8], bb[8];
#pragma unroll
            for (int i = 0; i < 8; i++) a[i]  = Asf[kk][ty * 8 + i];
#pragma unroll
            for (int j = 0; j < 8; j++) bb[j] = Bsf[kk][tx * 8 + j];
#pragma unroll
            for (int i = 0; i < 8; i++)
#pragma unroll
                for (int j = 0; j < 8; j++)
                    acc[i][j] = fmaf(a[i], bb[j], acc[i][j]);
        }
        __syncthreads();
    }

#pragma unroll
    for (int i = 0; i < 8; i++) {
        int m = bm + ty * 8 + i;
        float* dst = kvws + (size_t)m * TWO_D + n0 + tx * 8;
#pragma unroll
        for (int j = 0; j < 8; j += 4) {
            *(float4*)(dst + j) = make_float4(acc[i][j], acc[i][j + 1],
                                              acc[i][j + 2], acc[i][j + 3]);
        }
    }
}

__global__ __launch_bounds__(256) void rope_k_f32(float* __restrict__ kvws,
                                                  const float* __restrict__ freqs) {
    int gid = blockIdx.x * 256 + threadIdx.x;
    int m = gid >> 7;
    int p = gid & 127;
    int f = p & 15;
    int b = m / PPB;
    int r = m - b * PPB;
    int l, S, base, lg, inv;
    row_geom(r, l, S, base, lg, inv);
    int idx = r - base;
    int i = idx >> lg;
    int j = idx & (S - 1);
    float px = (float)(i * inv), py = (float)(j * inv), pl = (float)l;
    float ang = px * freqs[f] + py * freqs[16 + f] + pl * freqs[32 + f];
    float c = cosf(ang), s = sinf(ang);
    float2* kp = (float2*)kvws + (size_t)m * 256 + p;
    float2 v = *kp;
    *kp = make_float2(v.x * c - v.y * s, v.x * s + v.y * c);
}

__global__ __launch_bounds__(256) void attn_fused(const float* __restrict__ query,
                                                  const float* __restrict__ qpos,
                                                  const float* __restrict__ Wq,
                                                  const float* __restrict__ Wout,
                                                  const float* __restrict__ gamma,
                                                  const float* __restrict__ beta,
                                                  const float* __restrict__ freqs,
                                                  const float* __restrict__ kvws,
                                                  float* __restrict__ out) {
    __shared__ float qn[Dd];
    __shared__ __align__(16) float qsh[Dd];
    __shared__ float sL[NHh * KK];
    __shared__ int   kidx[KK];
    __shared__ float attnL[Dd];
    __shared__ float red[4];
    __shared__ float invS[NHh];

    const int q = blockIdx.x;
    const int t = threadIdx.x;
    const int wid = t >> 6;
    const int h = t >> 5, lane = t & 31;

    float x = query[q * Dd + t];
    float s = x;
#pragma unroll
    for (int mK = 32; mK >= 1; mK >>= 1) s += __shfl_xor(s, mK);
    if ((t & 63) == 0) red[wid] = s;
    __syncthreads();
    float mu = (red[0] + red[1] + red[2] + red[3]) * (1.0f / 256.0f);
    float dx = x - mu;
    float s2 = dx * dx;
#pragma unroll
    for (int mK = 32; mK >= 1; mK >>= 1) s2 += __shfl_xor(s2, mK);
    __syncthreads();
    if ((t & 63) == 0) red[wid] = s2;
    __syncthreads();
    float var = (red[0] + red[1] + red[2] + red[3]) * (1.0f / 256.0f);
    float rs = rsqrtf(var + 1e-5f);
    qn[t] = dx * rs * gamma[t] + beta[t];
    __syncthreads();

    float a0 = 0.f, a1 = 0.f, a2 = 0.f, a3 = 0.f;
#pragma unroll 8
    for (int d = 0; d < Dd; d += 4) {
        a0 = fmaf(qn[d + 0], Wq[(d + 0) * Dd + t], a0);
        a1 = fmaf(qn[d + 1], Wq[(d + 1) * Dd + t], a1);
        a2 = fmaf(qn[d + 2], Wq[(d + 2) * Dd + t], a2);
        a3 = fmaf(qn[d + 3], Wq[(d + 3) * Dd + t], a3);
    }
    float acc = (a0 + a1) + (a2 + a3);

    float qx = qpos[q * 4 + 1];
    float qy = qpos[q * 4 + 2];
    int   bb = (int)qpos[q * 4 + 0];
    {
        int f = (t & 31) >> 1;
        float ang = qx * freqs[f] + qy * freqs[16 + f] + 3.0f * freqs[32 + f];
        float c = cosf(ang), sn = sinf(ang);
        float partner = __shfl_xor(acc, 1);
        bool ev = !(t & 1);
        acc = ev ? (acc * c - partner * sn) : (partner * sn + acc * c);
    }
    qsh[t] = acc;

    if (t < KK) {
        int k = t;
        int S, base, off, sz, half, lg;
        if      (k < 9)  { S = 8;  base = 0;    off = k;      sz = 3; half = 1; lg = 3; }
        else if (k < 34) { S = 16; base = 64;   off = k - 9;  sz = 5; half = 2; lg = 4; }
        else if (k < 83) { S = 32; base = 320;  off = k - 34; sz = 7; half = 3; lg = 5; }
        else             { S = 64; base = 1344; off = k - 83; sz = 9; half = 4; lg = 6; }
        int di = off / sz - half;
        int dj = off % sz - half;
        float scal = (float)S * (1.0f / 64.0f);
        int ci = (int)floorf(qx * scal);
        int cj = (int)floorf(qy * scal);
        int i = ci + di, j = cj + dj;
        bool valid = (i >= 0) & (i < S) & (j >= 0) & (j < S);
        kidx[t] = valid ? (bb * PPB + base + (i << lg) + j) : -1;
    }
    __syncthreads();

    float4 qv[8];
    {
        const float4* qp = (const float4*)(qsh + h * HDd);
#pragma unroll
        for (int i = 0; i < 8; i++) qv[i] = qp[i];
    }
#pragma unroll
    for (int ct = 0; ct < 6; ++ct) {
        int k = ct * 32 + lane;
        if (k >= KK) break;
        int ki = kidx[k];
        int kr = ki < 0 ? 0 : ki;
        const float4* kp = (const float4*)(kvws + (size_t)kr * TWO_D + h * HDd);
        float c0 = 0.f, c1 = 0.f;
#pragma unroll
        for (int i = 0; i < 8; i += 2) {
            float4 k0v = kp[i], k1v = kp[i + 1];
            c0 = fmaf(qv[i].x, k0v.x, c0); c0 = fmaf(qv[i].y, k0v.y, c0);
            c0 = fmaf(qv[i].z, k0v.z, c0); c0 = fmaf(qv[i].w, k0v.w, c0);
            c1 = fmaf(qv[i + 1].x, k1v.x, c1); c1 = fmaf(qv[i + 1].y, k1v.y, c1);
            c1 = fmaf(qv[i + 1].z, k1v.z, c1); c1 = fmaf(qv[i + 1].w, k1v.w, c1);
        }
        sL[h * KK + k] = (ki >= 0) ? (c0 + c1) : -INFINITY;
    }
    __syncthreads();

    float mx = -INFINITY;
    for (int k = lane; k < KK; k += 32) mx = fmaxf(mx, sL[h * KK + k]);
#pragma unroll
    for (int mK = 16; mK >= 1; mK >>= 1) mx = fmaxf(mx, __shfl_xor(mx, mK));
    float se = 0.f;
    for (int k = lane; k < KK; k += 32) {
        float e = expf(sL[h * KK + k] - mx);
        sL[h * KK + k] = e;
        se += e;
    }
#pragma unroll
    for (int mK = 16; mK >= 1; mK >>= 1) se += __shfl_xor(se, mK);
    if (lane == 0) invS[h] = 1.0f / se;
    __syncthreads();

    float p0 = 0.f, p1 = 0.f, p2 = 0.f, p3 = 0.f;
#pragma unroll 4
    for (int k = 0; k < 164; k += 4) {
        int ki0 = kidx[k],     kr0 = ki0 < 0 ? 0 : ki0;
        int ki1 = kidx[k + 1], kr1 = ki1 < 0 ? 0 : ki1;
        int ki2 = kidx[k + 2], kr2 = ki2 < 0 ? 0 : ki2;
        int ki3 = kidx[k + 3], kr3 = ki3 < 0 ? 0 : ki3;
        p0 = fmaf(sL[h * KK + k],     kvws[(size_t)kr0 * TWO_D + Dd + t], p0);
        p1 = fmaf(sL[h * KK + k + 1], kvws[(size_t)kr1 * TWO_D + Dd + t], p1);
        p2 = fmaf(sL[h * KK + k + 2], kvws[(size_t)kr2 * TWO_D + Dd + t], p2);
        p3 = fmaf(sL[h * KK + k + 3], kvws[(size_t)kr3 * TWO_D + Dd + t], p3);
    }
    attnL[t] = ((p0 + p1) + (p2 + p3)) * invS[h];
    __syncthreads();

    float o0 = query[q * Dd + t], o1 = 0.f, o2 = 0.f, o3 = 0.f;
#pragma unroll 8
    for (int d = 0; d < Dd; d += 4) {
        o0 = fmaf(attnL[d + 0], Wout[(d + 0) * Dd + t], o0);
        o1 = fmaf(attnL[d + 1], Wout[(d + 1) * Dd + t], o1);
        o2 = fmaf(attnL[d + 2], Wout[(d + 2) * Dd + t], o2);
        o3 = fmaf(attnL[d + 3], Wout[(d + 3) * Dd + t], o3);
    }
    out[q * Dd + t] = (o0 + o1) + (o2 + o3);
}

// ---------------------------------------------------------------------------
extern "C" void kernel_launch(void* const* d_in, const int* in_sizes, int n_in,
                              void* d_out, int out_size, void* d_ws, size_t ws_size,
                              hipStream_t stream) {
    const float* query = (const float*)d_in[0];
    const float* qpos  = (const float*)d_in[1];
    const float* fmap  = (const float*)d_in[3];
    const float* gamma = (const float*)d_in[5];
    const float* beta  = (const float*)d_in[6];
    const float* Wq    = (const float*)d_in[7];
    const float* Wkv   = (const float*)d_in[8];
    const float* Wout  = (const float*)d_in[9];
    const float* freqs = (const float*)d_in[10];
    float* out = (float*)d_out;

    // flat workspace layout (kept identical to round-11-proven offsets)
    const size_t O_KV16   = 0;            // 22,282,240
    const size_t O_WKVHI  = 44564480;     //    262,144
    const size_t O_WKVLO  = 44826624;     //    262,144
    const size_t O_WQHI   = 45088768;     //    131,072
    const size_t O_WQLO   = 45219840;     //    131,072
    const size_t O_WOHI   = 45350912;     //    131,072
    const size_t O_WOLO   = 45481984;     //    131,072
    const size_t O_XHI    = 45613056;     //  1,048,576
    const size_t O_XLO    = 46661632;     //  1,048,576
    const size_t O_QR     = 47710208;     //  2,097,152
    const size_t O_PHI    = 49807360;     //  1,048,576
    const size_t O_PLO    = 50855936;     //  1,048,576
    const size_t need     = 51904512;

    if (ws_size >= need) {
        char* base = (char*)d_ws;
        unsigned short* kv16   = (unsigned short*)(base + O_KV16);
        unsigned short* WkvThi = (unsigned short*)(base + O_WKVHI);
        unsigned short* WkvTlo = (unsigned short*)(base + O_WKVLO);
        unsigned short* WqThi  = (unsigned short*)(base + O_WQHI);
        unsigned short* WqTlo  = (unsigned short*)(base + O_WQLO);
        unsigned short* WoThi  = (unsigned short*)(base + O_WOHI);
        unsigned short* WoTlo  = (unsigned short*)(base + O_WOLO);
        unsigned short* Xhi    = (unsigned short*)(base + O_XHI);
        unsigned short* Xlo    = (unsigned short*)(base + O_XLO);
        float*          qrw    = (float*)        (base + O_QR);
        unsigned short* Phi    = (unsigned short*)(base + O_PHI);
        unsigned short* Plo    = (unsigned short*)(base + O_PLO);

        prep<<<dim3(3072), 256, 0, stream>>>(Wkv, Wq, Wout, query, gamma, beta,
                                             WkvThi, WkvTlo, WqThi, WqTlo,
                                             WoThi, WoTlo, Xhi, Xlo);
        // 704 kv-blocks (24 early-exit) + 256 proj_q blocks riding the tail
        kvq_gemm<<<dim3(960), 256, 0, stream>>>(fmap, WkvThi, WkvTlo,
                                                Xhi, Xlo, WqThi, WqTlo,
                                                freqs, kv16, qrw);
        attn_core<<<dim3(NQ), 256, 0, stream>>>(qrw, qpos, kv16, freqs, Phi, Plo);
        proj_out<<<dim3(8, 32), 256, 0, stream>>>(Phi, Plo, WoThi, WoTlo,
                                                  out, query);
    } else {
        float* kvws = (float*)d_ws;
        kv_gemm<<<dim3(M_TOT / BMf, TWO_D / BNf), 256, 0, stream>>>(fmap, Wkv, kvws);
        rope_k_f32<<<dim3((M_TOT * 128) / 256), 256, 0, stream>>>(kvws, freqs);
        attn_fused<<<dim3(NQ), 256, 0, stream>>>(query, qpos, Wq, Wout, gamma, beta,
                                                 freqs, kvws, out);
    }
}